// Round 12
// baseline (60.837 us; speedup 1.0000x reference)
//
#include <hip/hip_runtime.h>
#include <hip/hip_bf16.h>

#define LL 50
#define DD 64
#define NCATS 1000
#define NRAT 5

// ws byte offsets
#define OFF_H    0          // ushort[1000*5*64] = 640000 B (bf16 H table)
#define OFF_M1T  640000     // ushort[64*64] bf16 (M1t[d][e] = (Wq Wk^T)[e][d])
#define OFF_WVOT 648192     // ushort[64*64] bf16 (Wvot[d][e] = (Wv Wo)[e][d])
#define OFF_BKQ  656384     // float[64]  (Wk @ bq)
#define OFF_BVO  656640     // float[64]  (bv @ Wo + bo)

typedef __attribute__((ext_vector_type(8))) short short8;
typedef __attribute__((ext_vector_type(4))) float f32x4;

union U4S8 { uint4 u4; short8 s8; };

__device__ __forceinline__ float rlanef(float v, int l) {
  return __uint_as_float(__builtin_amdgcn_readlane(__float_as_uint(v), l));
}
__device__ __forceinline__ unsigned short f2bf(float f) {  // RNE f32->bf16
  unsigned int u = __float_as_uint(f);
  u = (u + 0x7fffu + ((u >> 16) & 1u)) >> 16;
  return (unsigned short)u;
}
__device__ __forceinline__ unsigned int pk2bf(float lo, float hi) {
  return (unsigned int)f2bf(lo) | ((unsigned int)f2bf(hi) << 16);
}
__device__ __forceinline__ short8 pack8(float4 f0, float4 f1) {
  U4S8 t;
  t.u4.x = pk2bf(f0.x, f0.y); t.u4.y = pk2bf(f0.z, f0.w);
  t.u4.z = pk2bf(f1.x, f1.y); t.u4.w = pk2bf(f1.z, f1.w);
  return t.s8;
}

// ---------------- prep_fast: 65 blocks x 256 threads, MFMA tiles (unchanged r10) ----------------
__global__ __launch_bounds__(256) void prep_fast(
    const float* __restrict__ c2e, const float* __restrict__ r2e,
    const float* __restrict__ W1, const float* __restrict__ b1,
    const float* __restrict__ Wq, const float* __restrict__ bq,
    const float* __restrict__ Wk, const float* __restrict__ Wv,
    const float* __restrict__ Wo, const float* __restrict__ bv,
    const float* __restrict__ bo, char* __restrict__ ws) {
  unsigned short* H = (unsigned short*)(ws + OFF_H);
  unsigned short* M1T = (unsigned short*)(ws + OFF_M1T);
  unsigned short* WVOT = (unsigned short*)(ws + OFF_WVOT);
  float* BKQ = (float*)(ws + OFF_BKQ);
  float* BVO = (float*)(ws + OFF_BVO);

  __shared__ float AcS[16][68];
  __shared__ float ArS[5][68];

  const int tid = threadIdx.x;
  const int wid = tid >> 6;
  const int lane = tid & 63;
  const int kg = lane >> 4;
  const int rw = lane & 15;
  const int b = blockIdx.x;

  if (b < 63) {
    const int crow = min(b * 16 + rw, NCATS - 1);
    const float* __restrict__ xc = c2e + (size_t)crow * DD;
    const float* __restrict__ xr = r2e + (size_t)min(rw, NRAT - 1) * DD;
    short8 ac_[2], ar_[2], bfa[2], bfb[2];
#pragma unroll
    for (int ks = 0; ks < 2; ++ks) {
      const int k0 = ks * 32 + kg * 8;
      ac_[ks] = pack8(*(const float4*)(xc + k0), *(const float4*)(xc + k0 + 4));
      ar_[ks] = pack8(*(const float4*)(xr + k0), *(const float4*)(xr + k0 + 4));
      U4S8 ta, tb;
#pragma unroll
      for (int j = 0; j < 4; ++j) {
        const int k = k0 + 2 * j;
        const int col = wid * 16 + rw;
        ((unsigned int*)&ta)[j] = pk2bf(W1[(size_t)k * DD + col],
                                        W1[(size_t)(k + 1) * DD + col]);
        ((unsigned int*)&tb)[j] = pk2bf(W1[(size_t)(DD + k) * DD + col],
                                        W1[(size_t)(DD + k + 1) * DD + col]);
      }
      bfa[ks] = ta.s8;
      bfb[ks] = tb.s8;
    }
    f32x4 accc = {0.f, 0.f, 0.f, 0.f}, accr = {0.f, 0.f, 0.f, 0.f};
#pragma unroll
    for (int ks = 0; ks < 2; ++ks) {
      accc = __builtin_amdgcn_mfma_f32_16x16x32_bf16(ac_[ks], bfa[ks], accc, 0, 0, 0);
      accr = __builtin_amdgcn_mfma_f32_16x16x32_bf16(ar_[ks], bfb[ks], accr, 0, 0, 0);
    }
#pragma unroll
    for (int r = 0; r < 4; ++r) {
      const int m = kg * 4 + r;
      AcS[m][wid * 16 + rw] = accc[r];
      if (m < NRAT) ArS[m][wid * 16 + rw] = accr[r];
    }
    __syncthreads();

    const float b1v = b1[lane];
    float ar5[NRAT];
#pragma unroll
    for (int r = 0; r < NRAT; ++r) ar5[r] = ArS[r][lane] + b1v;
#pragma unroll
    for (int i = 0; i < 4; ++i) {
      const int vc = b * 16 + wid * 4 + i;
      if (vc < NCATS) {
        const float acv = AcS[wid * 4 + i][lane];
#pragma unroll
        for (int r = 0; r < NRAT; ++r) {
          H[((size_t)vc * NRAT + r) * DD + lane] = f2bf(fmaxf(acv + ar5[r], 0.f));
        }
      }
    }
  } else if (b == 63) {
    short8 aq[2];
#pragma unroll
    for (int ks = 0; ks < 2; ++ks) {
      const float* __restrict__ p = Wq + (size_t)(wid * 16 + rw) * DD + ks * 32 + kg * 8;
      aq[ks] = pack8(*(const float4*)(p), *(const float4*)(p + 4));
    }
#pragma unroll
    for (int n0 = 0; n0 < 4; ++n0) {
      f32x4 a = {0.f, 0.f, 0.f, 0.f};
#pragma unroll
      for (int ks = 0; ks < 2; ++ks) {
        const float* __restrict__ p = Wk + (size_t)(n0 * 16 + rw) * DD + ks * 32 + kg * 8;
        const short8 bf = pack8(*(const float4*)(p), *(const float4*)(p + 4));
        a = __builtin_amdgcn_mfma_f32_16x16x32_bf16(aq[ks], bf, a, 0, 0, 0);
      }
#pragma unroll
      for (int r = 0; r < 4; ++r) {
        M1T[(size_t)(n0 * 16 + rw) * DD + wid * 16 + kg * 4 + r] = f2bf(a[r]);
      }
    }
    if (wid == 0) {
      const float* __restrict__ wrow = Wk + (size_t)lane * DD;
      float a0 = 0.f, a1 = 0.f, a2 = 0.f, a3 = 0.f;
#pragma unroll
      for (int t = 0; t < DD; t += 4) {
        const float4 w4 = *(const float4*)(wrow + t);
        a0 = fmaf(w4.x, bq[t + 0], a0);
        a1 = fmaf(w4.y, bq[t + 1], a1);
        a2 = fmaf(w4.z, bq[t + 2], a2);
        a3 = fmaf(w4.w, bq[t + 3], a3);
      }
      BKQ[lane] = (a0 + a1) + (a2 + a3);
    }
  } else {
    short8 ao[2];
#pragma unroll
    for (int ks = 0; ks < 2; ++ks) {
      U4S8 t4;
#pragma unroll
      for (int j = 0; j < 4; ++j) {
        const int k = ks * 32 + kg * 8 + 2 * j;
        const int col = wid * 16 + rw;
        ((unsigned int*)&t4)[j] = pk2bf(Wo[(size_t)k * DD + col],
                                        Wo[(size_t)(k + 1) * DD + col]);
      }
      ao[ks] = t4.s8;
    }
#pragma unroll
    for (int n0 = 0; n0 < 4; ++n0) {
      f32x4 a = {0.f, 0.f, 0.f, 0.f};
#pragma unroll
      for (int ks = 0; ks < 2; ++ks) {
        const float* __restrict__ p = Wv + (size_t)(n0 * 16 + rw) * DD + ks * 32 + kg * 8;
        const short8 bf = pack8(*(const float4*)(p), *(const float4*)(p + 4));
        a = __builtin_amdgcn_mfma_f32_16x16x32_bf16(ao[ks], bf, a, 0, 0, 0);
      }
#pragma unroll
      for (int r = 0; r < 4; ++r) {
        WVOT[(size_t)(wid * 16 + kg * 4 + r) * DD + n0 * 16 + rw] = f2bf(a[r]);
      }
    }
    if (wid == 0) {
      float acc = bo[lane];
#pragma unroll 8
      for (int t = 0; t < DD; ++t) acc = fmaf(bv[t], Wo[(size_t)t * DD + lane], acc);
      BVO[lane] = acc;
    }
  }
}

// ---------------- main v2: barrier-free, wave-independent, 2 nodes/wave pipelined ----------------
// Each wave: G/scores/OUT all via replicated-A MFMA (C rows equal); LDS only as
// wave-local scratch (write->read, lgkmcnt-ordered, NO __syncthreads anywhere).
// Next node's idx/nodes/v2e loads issued before current node's compute (T14).
__global__ __launch_bounds__(256) void vc_main(
    const int* __restrict__ nodes, const int* __restrict__ hvc,
    const int* __restrict__ hr, const float* __restrict__ v2e,
    const char* __restrict__ ws, float* __restrict__ out, int N) {
  const unsigned short* __restrict__ H = (const unsigned short*)(ws + OFF_H);
  const unsigned short* __restrict__ M1T = (const unsigned short*)(ws + OFF_M1T);
  const unsigned short* __restrict__ WVOT = (const unsigned short*)(ws + OFF_WVOT);
  const float* __restrict__ BKQ = (const float*)(ws + OFF_BKQ);
  const float* __restrict__ BVO = (const float*)(ws + OFF_BVO);

  __shared__ float gS[4][68];     // wave-local scratch (wid row), no barrier
  __shared__ float ctxS[4][68];

  const int tid = threadIdx.x;
  const int wid = tid >> 6;
  const int lane = tid & 63;
  const int kg = lane >> 4;
  const int rw = lane & 15;
  const int lidx = (lane < LL) ? lane : 0;

  const int nwave = blockIdx.x * 4 + wid;   // 2 nodes per wave: 2*nwave, 2*nwave+1

  // ---- prefetch node 0 of this wave ----
  const int nA = min(nwave * 2, N - 1);
  int idx_cur = hvc[(size_t)nA * LL + lidx] * NRAT + hr[(size_t)nA * LL + lidx];
  int nid_cur = nodes[nA];
  float4 xf_cur[4];  // x[ks*32+kg*8 ..+8] as 2x float4 per ks
  {
    const float* __restrict__ xrow = v2e + (size_t)nid_cur * DD;
#pragma unroll
    for (int ks = 0; ks < 2; ++ks) {
      xf_cur[2 * ks + 0] = *(const float4*)(xrow + ks * 32 + kg * 8);
      xf_cur[2 * ks + 1] = *(const float4*)(xrow + ks * 32 + kg * 8 + 4);
    }
  }

  int idx_nxt = 0, nid_nxt = 0;
  float4 xf_nxt[4];

#pragma unroll
  for (int g = 0; g < 2; ++g) {
    const int n = min(nwave * 2 + g, N - 1);

    // ---- issue next node's loads (hidden under this node's compute) ----
    if (g == 0) {
      const int nB = min(nwave * 2 + 1, N - 1);
      idx_nxt = hvc[(size_t)nB * LL + lidx] * NRAT + hr[(size_t)nB * LL + lidx];
      nid_nxt = nodes[nB];
      const float* __restrict__ xrow = v2e + (size_t)nid_nxt * DD;
#pragma unroll
      for (int ks = 0; ks < 2; ++ks) {
        xf_nxt[2 * ks + 0] = *(const float4*)(xrow + ks * 32 + kg * 8);
        xf_nxt[2 * ks + 1] = *(const float4*)(xrow + ks * 32 + kg * 8 + 4);
      }
    }
    const int idx = idx_cur;

    // ---- G = x @ M1 + bkq via replicated-A MFMA (C rows equal, use a[0]) ----
    {
      short8 xa[2];
      xa[0] = pack8(xf_cur[0], xf_cur[1]);
      xa[1] = pack8(xf_cur[2], xf_cur[3]);
#pragma unroll
      for (int n0 = 0; n0 < 4; ++n0) {
        f32x4 a = {0.f, 0.f, 0.f, 0.f};
#pragma unroll
        for (int ks = 0; ks < 2; ++ks) {
          const short8 bf = *(const short8*)(M1T + (size_t)(n0 * 16 + rw) * DD + ks * 32 + kg * 8);
          a = __builtin_amdgcn_mfma_f32_16x16x32_bf16(xa[ks], bf, a, 0, 0, 0);
        }
        if (kg == 0) gS[wid][n0 * 16 + rw] = a[0] + BKQ[n0 * 16 + rw];
      }
    }
    // wave-local write->read: ordered by lgkmcnt, no barrier
    short8 ga[2];
#pragma unroll
    for (int ks = 0; ks < 2; ++ks) {
      const float* __restrict__ gp = &gS[wid][ks * 32 + kg * 8];
      ga[ks] = pack8(*(const float4*)(gp), *(const float4*)(gp + 4));
    }

    // ---- scores via MFMA, B-frags direct from global H (L2-hot) ----
    int bidx[4];
#pragma unroll
    for (int lt = 0; lt < 4; ++lt) bidx[lt] = __shfl(idx, lt * 16 + rw, 64);
    float s0, s1, s2, s3;
    {
      f32x4 a;
#pragma unroll
      for (int lt = 0; lt < 4; ++lt) {
        a = (f32x4){0.f, 0.f, 0.f, 0.f};
#pragma unroll
        for (int ks = 0; ks < 2; ++ks) {
          U4S8 hb;
          hb.u4 = *(const uint4*)(H + (size_t)bidx[lt] * DD + ks * 32 + kg * 8);
          a = __builtin_amdgcn_mfma_f32_16x16x32_bf16(ga[ks], hb.s8, a, 0, 0, 0);
        }
        if (lt == 0) s0 = a[0];
        else if (lt == 1) s1 = a[0];
        else if (lt == 2) s2 = a[0];
        else s3 = a[0];
      }
    }
    s0 *= 0.125f; s1 *= 0.125f; s2 *= 0.125f;
    s3 = (rw < 2) ? s3 * 0.125f : -INFINITY;   // slots 48,49 (q.bk cancels)

    // ---- softmax over 50 slots ----
    float m = fmaxf(fmaxf(s0, s1), fmaxf(s2, s3));
#pragma unroll
    for (int x = 1; x <= 8; x <<= 1) m = fmaxf(m, __shfl_xor(m, x, 64));
    float e0 = __expf(s0 - m), e1 = __expf(s1 - m), e2 = __expf(s2 - m);
    float e3 = (rw < 2) ? __expf(s3 - m) : 0.f;
    float Z = ((e0 + e1) + (e2 + e3));
#pragma unroll
    for (int x = 1; x <= 8; x <<= 1) Z += __shfl_xor(Z, x, 64);
    const float invZ = 1.f / Z;

    // ---- ctx[d=lane] = sum_l e_l * H[idx_l][d] / Z (coalesced 128B row reads) ----
    {
      float c0 = 0.f, c1 = 0.f;
#define CTX_BLOCK(EREG, BASE, CNT, CACC)                                   \
      _Pragma("unroll")                                                    \
      for (int j = 0; j < (CNT); ++j) {                                    \
        const int l = (BASE) + j;                                          \
        const int si = __builtin_amdgcn_readlane(idx, l);                  \
        const unsigned short hbb = H[(size_t)si * DD + lane];              \
        CACC = fmaf(__uint_as_float(((unsigned int)hbb) << 16),            \
                    rlanef(EREG, j), CACC);                                \
      }
      CTX_BLOCK(e0, 0, 16, c0)
      CTX_BLOCK(e1, 16, 16, c1)
      CTX_BLOCK(e2, 32, 16, c0)
      CTX_BLOCK(e3, 48, 2, c1)
#undef CTX_BLOCK
      ctxS[wid][lane] = (c0 + c1) * invZ;
    }

    // ---- OUT = ctx @ Wvo + bvo via replicated-A MFMA ----
    {
      short8 ca[2];
#pragma unroll
      for (int ks = 0; ks < 2; ++ks) {
        const float* __restrict__ cp = &ctxS[wid][ks * 32 + kg * 8];
        ca[ks] = pack8(*(const float4*)(cp), *(const float4*)(cp + 4));
      }
#pragma unroll
      for (int n0 = 0; n0 < 4; ++n0) {
        f32x4 a = {0.f, 0.f, 0.f, 0.f};
#pragma unroll
        for (int ks = 0; ks < 2; ++ks) {
          const short8 bf = *(const short8*)(WVOT + (size_t)(n0 * 16 + rw) * DD + ks * 32 + kg * 8);
          a = __builtin_amdgcn_mfma_f32_16x16x32_bf16(ca[ks], bf, a, 0, 0, 0);
        }
        if (kg == 0 && n < N) {
          out[(size_t)n * DD + n0 * 16 + rw] = a[0] + BVO[n0 * 16 + rw];
        }
      }
    }

    // ---- rotate prefetch ----
    idx_cur = idx_nxt;
    nid_cur = nid_nxt;
#pragma unroll
    for (int i = 0; i < 4; ++i) xf_cur[i] = xf_nxt[i];
  }
}

extern "C" void kernel_launch(void* const* d_in, const int* in_sizes, int n_in,
                              void* d_out, int out_size, void* d_ws, size_t ws_size,
                              hipStream_t stream) {
  const int* nodes = (const int*)d_in[0];
  const int* hvc = (const int*)d_in[1];
  const int* hr = (const int*)d_in[2];
  const float* c2e = (const float*)d_in[3];
  const float* v2e = (const float*)d_in[4];
  const float* r2e = (const float*)d_in[5];
  const float* W1 = (const float*)d_in[6];
  const float* b1 = (const float*)d_in[7];
  const float* Wq = (const float*)d_in[8];
  const float* bq = (const float*)d_in[9];
  const float* Wk = (const float*)d_in[10];
  const float* bk = (const float*)d_in[11];  // unused: q·bk cancels in softmax
  const float* Wv = (const float*)d_in[12];
  const float* bv = (const float*)d_in[13];
  const float* Wo = (const float*)d_in[14];
  const float* bo = (const float*)d_in[15];
  (void)bk;
  float* out = (float*)d_out;
  char* ws = (char*)d_ws;

  const int N = in_sizes[0];

  prep_fast<<<65, 256, 0, stream>>>(c2e, r2e, W1, b1, Wq, bq, Wk, Wv, Wo, bv, bo, ws);
  // 4 waves/block, 2 nodes/wave -> 8 nodes/block
  vc_main<<<(N + 7) / 8, 256, 0, stream>>>(nodes, hvc, hr, v2e, ws, out, N);
}

// Round 13
// 36.090 us; speedup vs baseline: 1.6857x; 1.6857x over previous
//
#include <hip/hip_runtime.h>
#include <hip/hip_bf16.h>

#define LL 50
#define DD 64
#define NCATS 1000
#define NRAT 5

// ws byte offsets
#define OFF_H    0          // ushort[1000*5*64] = 640000 B (bf16 H table)
#define OFF_M1T  640000     // ushort[64*64] bf16 (M1t[d][e] = (Wq Wk^T)[e][d])
#define OFF_WVOT 648192     // ushort[64*64] bf16 (Wvot[d][e] = (Wv Wo)[e][d])
#define OFF_BKQ  656384     // float[64]  (Wk @ bq)
#define OFF_BVO  656640     // float[64]  (bv @ Wo + bo)

typedef __attribute__((ext_vector_type(8))) short short8;
typedef __attribute__((ext_vector_type(4))) float f32x4;

union U4S8 { uint4 u4; short8 s8; };

__device__ __forceinline__ float rlanef(float v, int l) {
  return __uint_as_float(__builtin_amdgcn_readlane(__float_as_uint(v), l));
}
// HW packed f32->bf16 (RNE): 1 instr per pair (was ~10 VALU in bit-twiddle form)
__device__ __forceinline__ unsigned int pk2bf(float lo, float hi) {
  unsigned int r;
  asm("v_cvt_pk_bf16_f32 %0, %1, %2" : "=v"(r) : "v"(lo), "v"(hi));
  return r;
}
__device__ __forceinline__ unsigned short f2bf(float f) {
  unsigned int r;
  asm("v_cvt_pk_bf16_f32 %0, %1, %1" : "=v"(r) : "v"(f));
  return (unsigned short)r;
}
__device__ __forceinline__ short8 pack8(float4 f0, float4 f1) {
  U4S8 t;
  t.u4.x = pk2bf(f0.x, f0.y); t.u4.y = pk2bf(f0.z, f0.w);
  t.u4.z = pk2bf(f1.x, f1.y); t.u4.w = pk2bf(f1.z, f1.w);
  return t.s8;
}

// ---------------- prep_fast v2: 317 blocks x 256 threads ----------------
//  b in [0,315): tile t=b/5, rating r=b%5. Ac=c2e[t-tile]@W1a via MFMA
//    (recomputed per rating block - cheap), Ar[d]=r2e[r]@W1b via VALU,
//    store 16 cats x 64 d of H for rating r, coalesced.
//  b == 315: M1T (MFMA) + BKQ.  b == 316: WVOT (MFMA) + BVO.
__global__ __launch_bounds__(256) void prep_fast(
    const float* __restrict__ c2e, const float* __restrict__ r2e,
    const float* __restrict__ W1, const float* __restrict__ b1,
    const float* __restrict__ Wq, const float* __restrict__ bq,
    const float* __restrict__ Wk, const float* __restrict__ Wv,
    const float* __restrict__ Wo, const float* __restrict__ bv,
    const float* __restrict__ bo, char* __restrict__ ws) {
  unsigned short* H = (unsigned short*)(ws + OFF_H);
  unsigned short* M1T = (unsigned short*)(ws + OFF_M1T);
  unsigned short* WVOT = (unsigned short*)(ws + OFF_WVOT);
  float* BKQ = (float*)(ws + OFF_BKQ);
  float* BVO = (float*)(ws + OFF_BVO);

  __shared__ float AcS[16][68];

  const int tid = threadIdx.x;
  const int wid = tid >> 6;
  const int lane = tid & 63;
  const int kg = lane >> 4;
  const int rw = lane & 15;
  const int b = blockIdx.x;

  if (b < 315) {
    const int t = b / 5;
    const int r = b - t * 5;

    // ---- Ac = c2e[tile] @ W1a via MFMA (wave wid owns d-quarter wid) ----
    const int crow = min(t * 16 + rw, NCATS - 1);
    const float* __restrict__ xc = c2e + (size_t)crow * DD;
    f32x4 accc = {0.f, 0.f, 0.f, 0.f};
#pragma unroll
    for (int ks = 0; ks < 2; ++ks) {
      const int k0 = ks * 32 + kg * 8;
      const short8 ac_ = pack8(*(const float4*)(xc + k0), *(const float4*)(xc + k0 + 4));
      U4S8 ta;
#pragma unroll
      for (int j = 0; j < 4; ++j) {
        const int k = k0 + 2 * j;
        const int col = wid * 16 + rw;
        ((unsigned int*)&ta)[j] = pk2bf(W1[(size_t)k * DD + col],
                                        W1[(size_t)(k + 1) * DD + col]);
      }
      accc = __builtin_amdgcn_mfma_f32_16x16x32_bf16(ac_, ta.s8, accc, 0, 0, 0);
    }
#pragma unroll
    for (int rr = 0; rr < 4; ++rr) AcS[kg * 4 + rr][wid * 16 + rw] = accc[rr];

    // ---- Ar[d] = r2e[r] @ W1b + b1, d = lane (redundant across waves) ----
    const float* __restrict__ rrow = r2e + (size_t)r * DD;
    float a0 = b1[lane], a1 = 0.f, a2 = 0.f, a3 = 0.f;
#pragma unroll 4
    for (int e = 0; e < DD; e += 4) {
      a0 = fmaf(rrow[e + 0], W1[(size_t)(DD + e + 0) * DD + lane], a0);
      a1 = fmaf(rrow[e + 1], W1[(size_t)(DD + e + 1) * DD + lane], a1);
      a2 = fmaf(rrow[e + 2], W1[(size_t)(DD + e + 2) * DD + lane], a2);
      a3 = fmaf(rrow[e + 3], W1[(size_t)(DD + e + 3) * DD + lane], a3);
    }
    const float ar = (a0 + a1) + (a2 + a3);
    __syncthreads();

    // ---- store H for this rating: 16 cats x 64 d ----
#pragma unroll
    for (int i = 0; i < 4; ++i) {
      const int cat = (tid >> 6) + i * 4;
      const int vc = t * 16 + cat;
      if (vc < NCATS) {
        H[((size_t)vc * NRAT + r) * DD + lane] = f2bf(fmaxf(AcS[cat][lane] + ar, 0.f));
      }
    }
  } else if (b == 315) {
    short8 aq[2];
#pragma unroll
    for (int ks = 0; ks < 2; ++ks) {
      const float* __restrict__ p = Wq + (size_t)(wid * 16 + rw) * DD + ks * 32 + kg * 8;
      aq[ks] = pack8(*(const float4*)(p), *(const float4*)(p + 4));
    }
#pragma unroll
    for (int n0 = 0; n0 < 4; ++n0) {
      f32x4 a = {0.f, 0.f, 0.f, 0.f};
#pragma unroll
      for (int ks = 0; ks < 2; ++ks) {
        const float* __restrict__ p = Wk + (size_t)(n0 * 16 + rw) * DD + ks * 32 + kg * 8;
        const short8 bf = pack8(*(const float4*)(p), *(const float4*)(p + 4));
        a = __builtin_amdgcn_mfma_f32_16x16x32_bf16(aq[ks], bf, a, 0, 0, 0);
      }
#pragma unroll
      for (int r = 0; r < 4; ++r) {
        M1T[(size_t)(n0 * 16 + rw) * DD + wid * 16 + kg * 4 + r] = f2bf(a[r]);
      }
    }
    if (wid == 0) {
      const float* __restrict__ wrow = Wk + (size_t)lane * DD;
      float a0 = 0.f, a1 = 0.f, a2 = 0.f, a3 = 0.f;
#pragma unroll
      for (int t2 = 0; t2 < DD; t2 += 4) {
        const float4 w4 = *(const float4*)(wrow + t2);
        a0 = fmaf(w4.x, bq[t2 + 0], a0);
        a1 = fmaf(w4.y, bq[t2 + 1], a1);
        a2 = fmaf(w4.z, bq[t2 + 2], a2);
        a3 = fmaf(w4.w, bq[t2 + 3], a3);
      }
      BKQ[lane] = (a0 + a1) + (a2 + a3);
    }
  } else {
    short8 ao[2];
#pragma unroll
    for (int ks = 0; ks < 2; ++ks) {
      U4S8 t4;
#pragma unroll
      for (int j = 0; j < 4; ++j) {
        const int k = ks * 32 + kg * 8 + 2 * j;
        const int col = wid * 16 + rw;
        ((unsigned int*)&t4)[j] = pk2bf(Wo[(size_t)k * DD + col],
                                        Wo[(size_t)(k + 1) * DD + col]);
      }
      ao[ks] = t4.s8;
    }
#pragma unroll
    for (int n0 = 0; n0 < 4; ++n0) {
      f32x4 a = {0.f, 0.f, 0.f, 0.f};
#pragma unroll
      for (int ks = 0; ks < 2; ++ks) {
        const float* __restrict__ p = Wv + (size_t)(n0 * 16 + rw) * DD + ks * 32 + kg * 8;
        const short8 bf = pack8(*(const float4*)(p), *(const float4*)(p + 4));
        a = __builtin_amdgcn_mfma_f32_16x16x32_bf16(ao[ks], bf, a, 0, 0, 0);
      }
#pragma unroll
      for (int r = 0; r < 4; ++r) {
        WVOT[(size_t)(wid * 16 + kg * 4 + r) * DD + n0 * 16 + rw] = f2bf(a[r]);
      }
    }
    if (wid == 0) {
      float acc = bo[lane];
#pragma unroll 8
      for (int t2 = 0; t2 < DD; ++t2) acc = fmaf(bv[t2], Wo[(size_t)t2 * DD + lane], acc);
      BVO[lane] = acc;
    }
  }
}

// ---------------- main: EXACT r8/r10 structure (26us known-good), cvt_pk packs ----------------
__global__ __launch_bounds__(256, 5) void vc_main(
    const int* __restrict__ nodes, const int* __restrict__ hvc,
    const int* __restrict__ hr, const float* __restrict__ v2e,
    const char* __restrict__ ws, float* __restrict__ out, int N) {
  const unsigned short* __restrict__ H = (const unsigned short*)(ws + OFF_H);
  const unsigned short* __restrict__ M1T = (const unsigned short*)(ws + OFF_M1T);
  const unsigned short* __restrict__ WVOT = (const unsigned short*)(ws + OFF_WVOT);
  const float* __restrict__ BKQ = (const float*)(ws + OFF_BKQ);
  const float* __restrict__ BVO = (const float*)(ws + OFF_BVO);

  __shared__ __align__(16) char smem[25600 + 1088 + 1088];
  char* HlB = smem;                          // 4 waves x 50 rows x 128B, swizzled
  float* gS = (float*)(smem + 25600);        // [4][68] f32
  float* ctxS = (float*)(smem + 25600 + 1088);  // [4][68] f32

  const int tid = threadIdx.x;
  const int wid = tid >> 6;    // 0..3  (= node within block, = d-quarter n0)
  const int lane = tid & 63;
  const int kg = lane >> 4;    // 0..3
  const int rw = lane & 15;    // 0..15
  const int nb = blockIdx.x * 4;
  const int n = min(nb + wid, N - 1);

  // ---- history indices: lane l <-> slot l ----
  const int lidx = (lane < LL) ? lane : 0;
  const int idx = hvc[(size_t)n * LL + lidx] * NRAT + hr[(size_t)n * LL + lidx];

  // ---- async stage: 7 x global_load_lds, each = 8 rows (64 lanes x 16B) ----
  {
    const int chunk = lane & 7;
    char* wbase = HlB + wid * 6400;
#pragma unroll
    for (int i = 0; i < 7; ++i) {
      const int s = (i < 6) ? (i * 8 + (lane >> 3)) : (42 + (lane >> 3));
      const int sidx = __shfl(idx, s, 64);
      const char* src = (const char*)H + (size_t)sidx * 128 + ((chunk ^ (s & 7)) << 4);
      __builtin_amdgcn_global_load_lds(
          (const __attribute__((address_space(1))) void*)src,
          (__attribute__((address_space(3))) void*)(wbase + ((i < 6) ? i * 1024 : 5376)),
          16, 0, 0);
    }
  }

  // ---- G = X @ M1 + bkq : wave wid computes d-quarter n0==wid for the 4 nodes ----
  {
    const int node_id = nodes[min(nb + (rw & 3), N - 1)];
    const float* __restrict__ xrow = v2e + (size_t)node_id * DD;
    short8 xa[2];
#pragma unroll
    for (int ks = 0; ks < 2; ++ks) {
      xa[ks] = pack8(*(const float4*)(xrow + ks * 32 + kg * 8),
                     *(const float4*)(xrow + ks * 32 + kg * 8 + 4));
    }
    const int n0 = wid;
    f32x4 a = {0.f, 0.f, 0.f, 0.f};
#pragma unroll
    for (int ks = 0; ks < 2; ++ks) {
      const short8 bf = *(const short8*)(M1T + (n0 * 16 + rw) * DD + ks * 32 + kg * 8);
      a = __builtin_amdgcn_mfma_f32_16x16x32_bf16(xa[ks], bf, a, 0, 0, 0);
    }
    if (kg == 0) {   // C rows 0..3 = nodes 0..3
      const float bkqv = BKQ[n0 * 16 + rw];
#pragma unroll
      for (int r = 0; r < 4; ++r) gS[r * 68 + n0 * 16 + rw] = a[r] + bkqv;
    }
  }
  __syncthreads();
  asm volatile("s_waitcnt vmcnt(0)" ::: "memory");  // H-stage complete
  __builtin_amdgcn_sched_barrier(0);

  const unsigned short* __restrict__ wH = (const unsigned short*)(HlB + wid * 6400);

  // ---- scores via MFMA from LDS ----
  short8 ga[2];
#pragma unroll
  for (int ks = 0; ks < 2; ++ks) {
    const float* __restrict__ gp = gS + wid * 68 + ks * 32 + kg * 8;
    ga[ks] = pack8(*(const float4*)(gp), *(const float4*)(gp + 4));
  }
  float s0, s1, s2, s3;
  {
    f32x4 a;
#pragma unroll
    for (int lt = 0; lt < 4; ++lt) {
      const int s = lt * 16 + rw;
      a = (f32x4){0.f, 0.f, 0.f, 0.f};
#pragma unroll
      for (int ks = 0; ks < 2; ++ks) {
        const int c = (ks * 4 + kg) ^ (s & 7);
        U4S8 hb;
        hb.u4 = *(const uint4*)(wH + s * 64 + c * 8);
        a = __builtin_amdgcn_mfma_f32_16x16x32_bf16(ga[ks], hb.s8, a, 0, 0, 0);
      }
      if (lt == 0) s0 = a[0];
      else if (lt == 1) s1 = a[0];
      else if (lt == 2) s2 = a[0];
      else s3 = a[0];
    }
  }
  s0 *= 0.125f; s1 *= 0.125f; s2 *= 0.125f;
  s3 = (rw < 2) ? s3 * 0.125f : -INFINITY;

  // ---- softmax over 50 slots ----
  float m = fmaxf(fmaxf(s0, s1), fmaxf(s2, s3));
#pragma unroll
  for (int x = 1; x <= 8; x <<= 1) m = fmaxf(m, __shfl_xor(m, x, 64));
  float e0 = __expf(s0 - m), e1 = __expf(s1 - m), e2 = __expf(s2 - m);
  float e3 = (rw < 2) ? __expf(s3 - m) : 0.f;
  float Z = ((e0 + e1) + (e2 + e3));
#pragma unroll
  for (int x = 1; x <= 8; x <<= 1) Z += __shfl_xor(Z, x, 64);
  const float invZ = 1.f / Z;

  // ---- ctx[d=lane] = sum_l e_l * H[slot l][d] / Z, all from LDS ----
  {
    const int sub = (lane & 7) * 2;
    const int hi3 = lane >> 3;
    float c0 = 0.f, c1 = 0.f;
#define CTX_BLOCK(EREG, BASE, CNT, CACC)                                        \
    _Pragma("unroll")                                                           \
    for (int j = 0; j < (CNT); ++j) {                                           \
      const int l = (BASE) + j;                                                 \
      const unsigned short hbb = *(const unsigned short*)(                      \
          (const char*)wH + l * 128 + (((hi3 ^ (l & 7)) << 4) | sub));          \
      CACC = fmaf(__uint_as_float(((unsigned int)hbb) << 16),                   \
                  rlanef(EREG, j), CACC);                                       \
    }
    CTX_BLOCK(e0, 0, 16, c0)
    CTX_BLOCK(e1, 16, 16, c1)
    CTX_BLOCK(e2, 32, 16, c0)
    CTX_BLOCK(e3, 48, 2, c1)
#undef CTX_BLOCK
    ctxS[wid * 68 + lane] = (c0 + c1) * invZ;
  }
  __syncthreads();

  // ---- OUT = CTX @ Wvo + bvo : wave wid computes d-quarter n0==wid ----
  {
    short8 ca[2];
#pragma unroll
    for (int ks = 0; ks < 2; ++ks) {
      const float* __restrict__ cp = ctxS + (rw & 3) * 68 + ks * 32 + kg * 8;
      ca[ks] = pack8(*(const float4*)(cp), *(const float4*)(cp + 4));
    }
    const int n0 = wid;
    f32x4 a = {0.f, 0.f, 0.f, 0.f};
#pragma unroll
    for (int ks = 0; ks < 2; ++ks) {
      const short8 bf = *(const short8*)(WVOT + (n0 * 16 + rw) * DD + ks * 32 + kg * 8);
      a = __builtin_amdgcn_mfma_f32_16x16x32_bf16(ca[ks], bf, a, 0, 0, 0);
    }
    if (kg == 0) {
      const float bvov = BVO[n0 * 16 + rw];
#pragma unroll
      for (int r = 0; r < 4; ++r) {
        const int node = nb + r;
        if (node < N) out[(size_t)node * DD + n0 * 16 + rw] = a[r] + bvov;
      }
    }
  }
}

extern "C" void kernel_launch(void* const* d_in, const int* in_sizes, int n_in,
                              void* d_out, int out_size, void* d_ws, size_t ws_size,
                              hipStream_t stream) {
  const int* nodes = (const int*)d_in[0];
  const int* hvc = (const int*)d_in[1];
  const int* hr = (const int*)d_in[2];
  const float* c2e = (const float*)d_in[3];
  const float* v2e = (const float*)d_in[4];
  const float* r2e = (const float*)d_in[5];
  const float* W1 = (const float*)d_in[6];
  const float* b1 = (const float*)d_in[7];
  const float* Wq = (const float*)d_in[8];
  const float* bq = (const float*)d_in[9];
  const float* Wk = (const float*)d_in[10];
  const float* bk = (const float*)d_in[11];  // unused: q·bk cancels in softmax
  const float* Wv = (const float*)d_in[12];
  const float* bv = (const float*)d_in[13];
  const float* Wo = (const float*)d_in[14];
  const float* bo = (const float*)d_in[15];
  (void)bk;
  float* out = (float*)d_out;
  char* ws = (char*)d_ws;

  const int N = in_sizes[0];

  prep_fast<<<317, 256, 0, stream>>>(c2e, r2e, W1, b1, Wq, bq, Wk, Wv, Wo, bv, bo, ws);
  vc_main<<<(N + 3) / 4, 256, 0, stream>>>(nodes, hvc, hr, v2e, ws, out, N);
}

// Round 15
// 35.185 us; speedup vs baseline: 1.7291x; 1.0257x over previous
//
#include <hip/hip_runtime.h>
#include <hip/hip_bf16.h>

#define LL 50
#define DD 64
#define NCATS 1000
#define NRAT 5

// ws byte offsets
#define OFF_H    0          // ushort[1000*5*64] = 640000 B (bf16 H table)
#define OFF_M1T  640000     // ushort[64*64] bf16 (M1t[d][e] = (Wq Wk^T)[e][d])
#define OFF_WVOT 648192     // ushort[64*64] bf16 (Wvot[d][e] = (Wv Wo)[e][d])
#define OFF_BKQ  656384     // float[64]  (Wk @ bq)
#define OFF_BVO  656640     // float[64]  (bv @ Wo + bo)

typedef __attribute__((ext_vector_type(8))) short short8;
typedef __attribute__((ext_vector_type(4))) float f32x4;

union U4S8 { uint4 u4; short8 s8; };

__device__ __forceinline__ float rlanef(float v, int l) {
  return __uint_as_float(__builtin_amdgcn_readlane(__float_as_uint(v), l));
}
// HW packed f32->bf16 (RNE): 1 instr per pair
__device__ __forceinline__ unsigned int pk2bf(float lo, float hi) {
  unsigned int r;
  asm("v_cvt_pk_bf16_f32 %0, %1, %2" : "=v"(r) : "v"(lo), "v"(hi));
  return r;
}
__device__ __forceinline__ unsigned short f2bf(float f) {
  unsigned int r;
  asm("v_cvt_pk_bf16_f32 %0, %1, %1" : "=v"(r) : "v"(f));
  return (unsigned short)r;
}
__device__ __forceinline__ short8 pack8(float4 f0, float4 f1) {
  U4S8 t;
  t.u4.x = pk2bf(f0.x, f0.y); t.u4.y = pk2bf(f0.z, f0.w);
  t.u4.z = pk2bf(f1.x, f1.y); t.u4.w = pk2bf(f1.z, f1.w);
  return t.s8;
}

// ---------------- prep_fast: BYTE-IDENTICAL to round 13 (known good) ----------------
__global__ __launch_bounds__(256) void prep_fast(
    const float* __restrict__ c2e, const float* __restrict__ r2e,
    const float* __restrict__ W1, const float* __restrict__ b1,
    const float* __restrict__ Wq, const float* __restrict__ bq,
    const float* __restrict__ Wk, const float* __restrict__ Wv,
    const float* __restrict__ Wo, const float* __restrict__ bv,
    const float* __restrict__ bo, char* __restrict__ ws) {
  unsigned short* H = (unsigned short*)(ws + OFF_H);
  unsigned short* M1T = (unsigned short*)(ws + OFF_M1T);
  unsigned short* WVOT = (unsigned short*)(ws + OFF_WVOT);
  float* BKQ = (float*)(ws + OFF_BKQ);
  float* BVO = (float*)(ws + OFF_BVO);

  __shared__ float AcS[16][68];

  const int tid = threadIdx.x;
  const int wid = tid >> 6;
  const int lane = tid & 63;
  const int kg = lane >> 4;
  const int rw = lane & 15;
  const int b = blockIdx.x;

  if (b < 315) {
    const int t = b / 5;
    const int r = b - t * 5;

    // ---- Ac = c2e[tile] @ W1a via MFMA (wave wid owns d-quarter wid) ----
    const int crow = min(t * 16 + rw, NCATS - 1);
    const float* __restrict__ xc = c2e + (size_t)crow * DD;
    f32x4 accc = {0.f, 0.f, 0.f, 0.f};
#pragma unroll
    for (int ks = 0; ks < 2; ++ks) {
      const int k0 = ks * 32 + kg * 8;
      const short8 ac_ = pack8(*(const float4*)(xc + k0), *(const float4*)(xc + k0 + 4));
      U4S8 ta;
#pragma unroll
      for (int j = 0; j < 4; ++j) {
        const int k = k0 + 2 * j;
        const int col = wid * 16 + rw;
        ((unsigned int*)&ta)[j] = pk2bf(W1[(size_t)k * DD + col],
                                        W1[(size_t)(k + 1) * DD + col]);
      }
      accc = __builtin_amdgcn_mfma_f32_16x16x32_bf16(ac_, ta.s8, accc, 0, 0, 0);
    }
#pragma unroll
    for (int rr = 0; rr < 4; ++rr) AcS[kg * 4 + rr][wid * 16 + rw] = accc[rr];

    // ---- Ar[d] = r2e[r] @ W1b + b1, d = lane (redundant across waves) ----
    const float* __restrict__ rrow = r2e + (size_t)r * DD;
    float a0 = b1[lane], a1 = 0.f, a2 = 0.f, a3 = 0.f;
#pragma unroll 4
    for (int e = 0; e < DD; e += 4) {
      a0 = fmaf(rrow[e + 0], W1[(size_t)(DD + e + 0) * DD + lane], a0);
      a1 = fmaf(rrow[e + 1], W1[(size_t)(DD + e + 1) * DD + lane], a1);
      a2 = fmaf(rrow[e + 2], W1[(size_t)(DD + e + 2) * DD + lane], a2);
      a3 = fmaf(rrow[e + 3], W1[(size_t)(DD + e + 3) * DD + lane], a3);
    }
    const float ar = (a0 + a1) + (a2 + a3);
    __syncthreads();

    // ---- store H for this rating: 16 cats x 64 d ----
#pragma unroll
    for (int i = 0; i < 4; ++i) {
      const int cat = (tid >> 6) + i * 4;
      const int vc = t * 16 + cat;
      if (vc < NCATS) {
        H[((size_t)vc * NRAT + r) * DD + lane] = f2bf(fmaxf(AcS[cat][lane] + ar, 0.f));
      }
    }
  } else if (b == 315) {
    short8 aq[2];
#pragma unroll
    for (int ks = 0; ks < 2; ++ks) {
      const float* __restrict__ p = Wq + (size_t)(wid * 16 + rw) * DD + ks * 32 + kg * 8;
      aq[ks] = pack8(*(const float4*)(p), *(const float4*)(p + 4));
    }
#pragma unroll
    for (int n0 = 0; n0 < 4; ++n0) {
      f32x4 a = {0.f, 0.f, 0.f, 0.f};
#pragma unroll
      for (int ks = 0; ks < 2; ++ks) {
        const float* __restrict__ p = Wk + (size_t)(n0 * 16 + rw) * DD + ks * 32 + kg * 8;
        const short8 bf = pack8(*(const float4*)(p), *(const float4*)(p + 4));
        a = __builtin_amdgcn_mfma_f32_16x16x32_bf16(aq[ks], bf, a, 0, 0, 0);
      }
#pragma unroll
      for (int r = 0; r < 4; ++r) {
        M1T[(size_t)(n0 * 16 + rw) * DD + wid * 16 + kg * 4 + r] = f2bf(a[r]);
      }
    }
    if (wid == 0) {
      const float* __restrict__ wrow = Wk + (size_t)lane * DD;
      float a0 = 0.f, a1 = 0.f, a2 = 0.f, a3 = 0.f;
#pragma unroll
      for (int t2 = 0; t2 < DD; t2 += 4) {
        const float4 w4 = *(const float4*)(wrow + t2);
        a0 = fmaf(w4.x, bq[t2 + 0], a0);
        a1 = fmaf(w4.y, bq[t2 + 1], a1);
        a2 = fmaf(w4.z, bq[t2 + 2], a2);
        a3 = fmaf(w4.w, bq[t2 + 3], a3);
      }
      BKQ[lane] = (a0 + a1) + (a2 + a3);
    }
  } else {
    short8 ao[2];
#pragma unroll
    for (int ks = 0; ks < 2; ++ks) {
      U4S8 t4;
#pragma unroll
      for (int j = 0; j < 4; ++j) {
        const int k = ks * 32 + kg * 8 + 2 * j;
        const int col = wid * 16 + rw;
        ((unsigned int*)&t4)[j] = pk2bf(Wo[(size_t)k * DD + col],
                                        Wo[(size_t)(k + 1) * DD + col]);
      }
      ao[ks] = t4.s8;
    }
#pragma unroll
    for (int n0 = 0; n0 < 4; ++n0) {
      f32x4 a = {0.f, 0.f, 0.f, 0.f};
#pragma unroll
      for (int ks = 0; ks < 2; ++ks) {
        const float* __restrict__ p = Wv + (size_t)(n0 * 16 + rw) * DD + ks * 32 + kg * 8;
        const short8 bf = pack8(*(const float4*)(p), *(const float4*)(p + 4));
        a = __builtin_amdgcn_mfma_f32_16x16x32_bf16(ao[ks], bf, a, 0, 0, 0);
      }
#pragma unroll
      for (int r = 0; r < 4; ++r) {
        WVOT[(size_t)(wid * 16 + kg * 4 + r) * DD + n0 * 16 + rw] = f2bf(a[r]);
      }
    }
    if (wid == 0) {
      float acc = bo[lane];
#pragma unroll 8
      for (int t2 = 0; t2 < DD; ++t2) acc = fmaf(bv[t2], Wo[(size_t)t2 * DD + lane], acc);
      BVO[lane] = acc;
    }
  }
}

// ---------------- main: r13 structure, ONLY change = gS/ctxS overlay (26,688B LDS, 6 blk/CU) ----------------
// Overlay safety: G writes rows 0..3 pre-barrier-1; each wave then reads ONLY its
// own row (ga, data-dep ordered before its own ctx write); ctx overwrites only
// its own row; OUT reads rows 0..3 post-barrier-2. No cross-wave hazard.
__global__ __launch_bounds__(256, 6) void vc_main(
    const int* __restrict__ nodes, const int* __restrict__ hvc,
    const int* __restrict__ hr, const float* __restrict__ v2e,
    const char* __restrict__ ws, float* __restrict__ out, int N) {
  const unsigned short* __restrict__ H = (const unsigned short*)(ws + OFF_H);
  const unsigned short* __restrict__ M1T = (const unsigned short*)(ws + OFF_M1T);
  const unsigned short* __restrict__ WVOT = (const unsigned short*)(ws + OFF_WVOT);
  const float* __restrict__ BKQ = (const float*)(ws + OFF_BKQ);
  const float* __restrict__ BVO = (const float*)(ws + OFF_BVO);

  __shared__ __align__(16) char smem[25600 + 1088];
  char* HlB = smem;                     // 4 waves x 50 rows x 128B, swizzled
  float* sS = (float*)(smem + 25600);   // [4][68] f32 (g, then ctx, per node row)

  const int tid = threadIdx.x;
  const int wid = tid >> 6;    // 0..3  (= node within block, = d-quarter n0)
  const int lane = tid & 63;
  const int kg = lane >> 4;    // 0..3
  const int rw = lane & 15;    // 0..15
  const int nb = blockIdx.x * 4;
  const int n = min(nb + wid, N - 1);

  // ---- history indices: lane l <-> slot l ----
  const int lidx = (lane < LL) ? lane : 0;
  const int idx = hvc[(size_t)n * LL + lidx] * NRAT + hr[(size_t)n * LL + lidx];

  // ---- async stage: 7 x global_load_lds, each = 8 rows (64 lanes x 16B) ----
  {
    const int chunk = lane & 7;
    char* wbase = HlB + wid * 6400;
#pragma unroll
    for (int i = 0; i < 7; ++i) {
      const int s = (i < 6) ? (i * 8 + (lane >> 3)) : (42 + (lane >> 3));
      const int sidx = __shfl(idx, s, 64);
      const char* src = (const char*)H + (size_t)sidx * 128 + ((chunk ^ (s & 7)) << 4);
      __builtin_amdgcn_global_load_lds(
          (const __attribute__((address_space(1))) void*)src,
          (__attribute__((address_space(3))) void*)(wbase + ((i < 6) ? i * 1024 : 5376)),
          16, 0, 0);
    }
  }

  // ---- G = X @ M1 + bkq : wave wid computes d-quarter n0==wid for the 4 nodes ----
  {
    const int node_id = nodes[min(nb + (rw & 3), N - 1)];
    const float* __restrict__ xrow = v2e + (size_t)node_id * DD;
    short8 xa[2];
#pragma unroll
    for (int ks = 0; ks < 2; ++ks) {
      xa[ks] = pack8(*(const float4*)(xrow + ks * 32 + kg * 8),
                     *(const float4*)(xrow + ks * 32 + kg * 8 + 4));
    }
    const int n0 = wid;
    f32x4 a = {0.f, 0.f, 0.f, 0.f};
#pragma unroll
    for (int ks = 0; ks < 2; ++ks) {
      const short8 bf = *(const short8*)(M1T + (n0 * 16 + rw) * DD + ks * 32 + kg * 8);
      a = __builtin_amdgcn_mfma_f32_16x16x32_bf16(xa[ks], bf, a, 0, 0, 0);
    }
    if (kg == 0) {   // C rows 0..3 = nodes 0..3
      const float bkqv = BKQ[n0 * 16 + rw];
#pragma unroll
      for (int r = 0; r < 4; ++r) sS[r * 68 + n0 * 16 + rw] = a[r] + bkqv;
    }
  }
  __syncthreads();
  asm volatile("s_waitcnt vmcnt(0)" ::: "memory");  // H-stage complete
  __builtin_amdgcn_sched_barrier(0);

  const unsigned short* __restrict__ wH = (const unsigned short*)(HlB + wid * 6400);

  // ---- scores via MFMA from LDS ----
  short8 ga[2];
#pragma unroll
  for (int ks = 0; ks < 2; ++ks) {
    const float* __restrict__ gp = sS + wid * 68 + ks * 32 + kg * 8;
    ga[ks] = pack8(*(const float4*)(gp), *(const float4*)(gp + 4));
  }
  float s0, s1, s2, s3;
  {
    f32x4 a;
#pragma unroll
    for (int lt = 0; lt < 4; ++lt) {
      const int s = lt * 16 + rw;
      a = (f32x4){0.f, 0.f, 0.f, 0.f};
#pragma unroll
      for (int ks = 0; ks < 2; ++ks) {
        const int c = (ks * 4 + kg) ^ (s & 7);
        U4S8 hb;
        hb.u4 = *(const uint4*)(wH + s * 64 + c * 8);
        a = __builtin_amdgcn_mfma_f32_16x16x32_bf16(ga[ks], hb.s8, a, 0, 0, 0);
      }
      if (lt == 0) s0 = a[0];
      else if (lt == 1) s1 = a[0];
      else if (lt == 2) s2 = a[0];
      else s3 = a[0];
    }
  }
  s0 *= 0.125f; s1 *= 0.125f; s2 *= 0.125f;
  s3 = (rw < 2) ? s3 * 0.125f : -INFINITY;

  // ---- softmax over 50 slots ----
  float m = fmaxf(fmaxf(s0, s1), fmaxf(s2, s3));
#pragma unroll
  for (int x = 1; x <= 8; x <<= 1) m = fmaxf(m, __shfl_xor(m, x, 64));
  float e0 = __expf(s0 - m), e1 = __expf(s1 - m), e2 = __expf(s2 - m);
  float e3 = (rw < 2) ? __expf(s3 - m) : 0.f;
  float Z = ((e0 + e1) + (e2 + e3));
#pragma unroll
  for (int x = 1; x <= 8; x <<= 1) Z += __shfl_xor(Z, x, 64);
  const float invZ = 1.f / Z;

  // ---- ctx[d=lane] = sum_l e_l * H[slot l][d] / Z, all from LDS ----
  {
    const int sub = (lane & 7) * 2;
    const int hi3 = lane >> 3;
    float c0 = 0.f, c1 = 0.f;
#define CTX_BLOCK(EREG, BASE, CNT, CACC)                                        \
    _Pragma("unroll")                                                           \
    for (int j = 0; j < (CNT); ++j) {                                           \
      const int l = (BASE) + j;                                                 \
      const unsigned short hbb = *(const unsigned short*)(                      \
          (const char*)wH + l * 128 + (((hi3 ^ (l & 7)) << 4) | sub));          \
      CACC = fmaf(__uint_as_float(((unsigned int)hbb) << 16),                   \
                  rlanef(EREG, j), CACC);                                       \
    }
    CTX_BLOCK(e0, 0, 16, c0)
    CTX_BLOCK(e1, 16, 16, c1)
    CTX_BLOCK(e2, 32, 16, c0)
    CTX_BLOCK(e3, 48, 2, c1)
#undef CTX_BLOCK
    sS[wid * 68 + lane] = (c0 + c1) * invZ;   // ctx overwrites own row
  }
  __syncthreads();

  // ---- OUT = CTX @ Wvo + bvo : wave wid computes d-quarter n0==wid ----
  {
    short8 ca[2];
#pragma unroll
    for (int ks = 0; ks < 2; ++ks) {
      const float* __restrict__ cp = sS + (rw & 3) * 68 + ks * 32 + kg * 8;
      ca[ks] = pack8(*(const float4*)(cp), *(const float4*)(cp + 4));
    }
    const int n0 = wid;
    f32x4 a = {0.f, 0.f, 0.f, 0.f};
#pragma unroll
    for (int ks = 0; ks < 2; ++ks) {
      const short8 bf = *(const short8*)(WVOT + (n0 * 16 + rw) * DD + ks * 32 + kg * 8);
      a = __builtin_amdgcn_mfma_f32_16x16x32_bf16(ca[ks], bf, a, 0, 0, 0);
    }
    if (kg == 0) {
      const float bvov = BVO[n0 * 16 + rw];
#pragma unroll
      for (int r = 0; r < 4; ++r) {
        const int node = nb + r;
        if (node < N) out[(size_t)node * DD + n0 * 16 + rw] = a[r] + bvov;
      }
    }
  }
}

extern "C" void kernel_launch(void* const* d_in, const int* in_sizes, int n_in,
                              void* d_out, int out_size, void* d_ws, size_t ws_size,
                              hipStream_t stream) {
  const int* nodes = (const int*)d_in[0];
  const int* hvc = (const int*)d_in[1];
  const int* hr = (const int*)d_in[2];
  const float* c2e = (const float*)d_in[3];
  const float* v2e = (const float*)d_in[4];
  const float* r2e = (const float*)d_in[5];
  const float* W1 = (const float*)d_in[6];
  const float* b1 = (const float*)d_in[7];
  const float* Wq = (const float*)d_in[8];
  const float* bq = (const float*)d_in[9];
  const float* Wk = (const float*)d_in[10];
  const float* bk = (const float*)d_in[11];  // unused: q·bk cancels in softmax
  const float* Wv = (const float*)d_in[12];
  const float* bv = (const float*)d_in[13];
  const float* Wo = (const float*)d_in[14];
  const float* bo = (const float*)d_in[15];
  (void)bk;
  float* out = (float*)d_out;
  char* ws = (char*)d_ws;

  const int N = in_sizes[0];

  prep_fast<<<317, 256, 0, stream>>>(c2e, r2e, W1, b1, Wq, bq, Wk, Wv, Wo, bv, bo, ws);
  vc_main<<<(N + 3) / 4, 256, 0, stream>>>(nodes, hvc, hr, v2e, ws, out, N);
}

// Round 17
// 35.109 us; speedup vs baseline: 1.7328x; 1.0022x over previous
//
#include <hip/hip_runtime.h>
#include <hip/hip_bf16.h>

#define LL 50
#define DD 64
#define NCATS 1000
#define NRAT 5

// ws byte offsets
#define OFF_H    0          // ushort[1000*5*64] = 640000 B (bf16 H table)
#define OFF_M1T  640000     // ushort[64*64] bf16 (M1t[d][e] = (Wq Wk^T)[e][d])
#define OFF_WVOT 648192     // ushort[64*64] bf16 (Wvot[d][e] = (Wv Wo)[e][d])
#define OFF_BKQ  656384     // float[64]  (Wk @ bq)
#define OFF_BVO  656640     // float[64]  (bv @ Wo + bo)

typedef __attribute__((ext_vector_type(8))) short short8;
typedef __attribute__((ext_vector_type(4))) float f32x4;

union U4S8 { uint4 u4; short8 s8; };

__device__ __forceinline__ float rlanef(float v, int l) {
  return __uint_as_float(__builtin_amdgcn_readlane(__float_as_uint(v), l));
}
// HW packed f32->bf16 (RNE): 1 instr per pair
__device__ __forceinline__ unsigned int pk2bf(float lo, float hi) {
  unsigned int r;
  asm("v_cvt_pk_bf16_f32 %0, %1, %2" : "=v"(r) : "v"(lo), "v"(hi));
  return r;
}
__device__ __forceinline__ unsigned short f2bf(float f) {
  unsigned int r;
  asm("v_cvt_pk_bf16_f32 %0, %1, %1" : "=v"(r) : "v"(f));
  return (unsigned short)r;
}
__device__ __forceinline__ short8 pack8(float4 f0, float4 f1) {
  U4S8 t;
  t.u4.x = pk2bf(f0.x, f0.y); t.u4.y = pk2bf(f0.z, f0.w);
  t.u4.z = pk2bf(f1.x, f1.y); t.u4.w = pk2bf(f1.z, f1.w);
  return t.s8;
}

// ---------------- prep_v3: 252 blocks x 256, single kernel ----------------
//  b < 250 : wave = one category vc. ac[d]=c2e[vc]@W1a (f32 VALU, c2e row is
//            wave-uniform -> scalar operands; W1 column loads coalesced);
//            r0..r4[d]=r2e[r]@W1b in the SAME e-loop (6 independent chains).
//            Store 5 H rows = bf16(relu(ac + rr + b1)). No intermediates.
//  b == 250: M1T (MFMA) + BKQ   [r13-verbatim body]
//  b == 251: WVOT (MFMA) + BVO  [r13-verbatim body]
__global__ __launch_bounds__(256) void prep_v3(
    const float* __restrict__ c2e, const float* __restrict__ r2e,
    const float* __restrict__ W1, const float* __restrict__ b1,
    const float* __restrict__ Wq, const float* __restrict__ bq,
    const float* __restrict__ Wk, const float* __restrict__ Wv,
    const float* __restrict__ Wo, const float* __restrict__ bv,
    const float* __restrict__ bo, char* __restrict__ ws) {
  unsigned short* H = (unsigned short*)(ws + OFF_H);
  unsigned short* M1T = (unsigned short*)(ws + OFF_M1T);
  unsigned short* WVOT = (unsigned short*)(ws + OFF_WVOT);
  float* BKQ = (float*)(ws + OFF_BKQ);
  float* BVO = (float*)(ws + OFF_BVO);

  const int tid = threadIdx.x;
  const int wid = tid >> 6;
  const int lane = tid & 63;
  const int kg = lane >> 4;
  const int rw = lane & 15;
  const int b = blockIdx.x;

  if (b < 250) {
    // wave-uniform category index -> scalar loads for c2e row
    const int vc = __builtin_amdgcn_readfirstlane(b * 4 + wid);  // 250*4 = 1000
    const float* __restrict__ crow = c2e + (size_t)vc * DD;
    float ac = 0.f, q0 = 0.f, q1 = 0.f, q2 = 0.f, q3 = 0.f, q4 = 0.f;
#pragma unroll 8
    for (int e = 0; e < DD; ++e) {
      const float wa = W1[(size_t)e * DD + lane];         // coalesced
      const float wb = W1[(size_t)(DD + e) * DD + lane];  // coalesced
      ac = fmaf(crow[e], wa, ac);                         // scalar x vector
      q0 = fmaf(r2e[0 * DD + e], wb, q0);
      q1 = fmaf(r2e[1 * DD + e], wb, q1);
      q2 = fmaf(r2e[2 * DD + e], wb, q2);
      q3 = fmaf(r2e[3 * DD + e], wb, q3);
      q4 = fmaf(r2e[4 * DD + e], wb, q4);
    }
    const float base = ac + b1[lane];
    unsigned short* __restrict__ hrow = H + (size_t)vc * NRAT * DD + lane;
    hrow[0 * DD] = f2bf(fmaxf(base + q0, 0.f));
    hrow[1 * DD] = f2bf(fmaxf(base + q1, 0.f));
    hrow[2 * DD] = f2bf(fmaxf(base + q2, 0.f));
    hrow[3 * DD] = f2bf(fmaxf(base + q3, 0.f));
    hrow[4 * DD] = f2bf(fmaxf(base + q4, 0.f));
  } else if (b == 250) {
    short8 aq[2];
#pragma unroll
    for (int ks = 0; ks < 2; ++ks) {
      const float* __restrict__ p = Wq + (size_t)(wid * 16 + rw) * DD + ks * 32 + kg * 8;
      aq[ks] = pack8(*(const float4*)(p), *(const float4*)(p + 4));
    }
#pragma unroll
    for (int n0 = 0; n0 < 4; ++n0) {
      f32x4 a = {0.f, 0.f, 0.f, 0.f};
#pragma unroll
      for (int ks = 0; ks < 2; ++ks) {
        const float* __restrict__ p = Wk + (size_t)(n0 * 16 + rw) * DD + ks * 32 + kg * 8;
        const short8 bf = pack8(*(const float4*)(p), *(const float4*)(p + 4));
        a = __builtin_amdgcn_mfma_f32_16x16x32_bf16(aq[ks], bf, a, 0, 0, 0);
      }
#pragma unroll
      for (int r = 0; r < 4; ++r) {
        M1T[(size_t)(n0 * 16 + rw) * DD + wid * 16 + kg * 4 + r] = f2bf(a[r]);
      }
    }
    if (wid == 0) {
      const float* __restrict__ wrow = Wk + (size_t)lane * DD;
      float a0 = 0.f, a1 = 0.f, a2 = 0.f, a3 = 0.f;
#pragma unroll
      for (int t2 = 0; t2 < DD; t2 += 4) {
        const float4 w4 = *(const float4*)(wrow + t2);
        a0 = fmaf(w4.x, bq[t2 + 0], a0);
        a1 = fmaf(w4.y, bq[t2 + 1], a1);
        a2 = fmaf(w4.z, bq[t2 + 2], a2);
        a3 = fmaf(w4.w, bq[t2 + 3], a3);
      }
      BKQ[lane] = (a0 + a1) + (a2 + a3);
    }
  } else {
    short8 ao[2];
#pragma unroll
    for (int ks = 0; ks < 2; ++ks) {
      U4S8 t4;
#pragma unroll
      for (int j = 0; j < 4; ++j) {
        const int k = ks * 32 + kg * 8 + 2 * j;
        const int col = wid * 16 + rw;
        ((unsigned int*)&t4)[j] = pk2bf(Wo[(size_t)k * DD + col],
                                        Wo[(size_t)(k + 1) * DD + col]);
      }
      ao[ks] = t4.s8;
    }
#pragma unroll
    for (int n0 = 0; n0 < 4; ++n0) {
      f32x4 a = {0.f, 0.f, 0.f, 0.f};
#pragma unroll
      for (int ks = 0; ks < 2; ++ks) {
        const float* __restrict__ p = Wv + (size_t)(n0 * 16 + rw) * DD + ks * 32 + kg * 8;
        const short8 bf = pack8(*(const float4*)(p), *(const float4*)(p + 4));
        a = __builtin_amdgcn_mfma_f32_16x16x32_bf16(ao[ks], bf, a, 0, 0, 0);
      }
#pragma unroll
      for (int r = 0; r < 4; ++r) {
        WVOT[(size_t)(wid * 16 + kg * 4 + r) * DD + n0 * 16 + rw] = f2bf(a[r]);
      }
    }
    if (wid == 0) {
      float acc = bo[lane];
#pragma unroll 8
      for (int t2 = 0; t2 < DD; ++t2) acc = fmaf(bv[t2], Wo[(size_t)t2 * DD + lane], acc);
      BVO[lane] = acc;
    }
  }
}

// ---------------- main: BYTE-IDENTICAL to round 15 (passed, 26.7KB LDS overlay) ----------------
__global__ __launch_bounds__(256, 6) void vc_main(
    const int* __restrict__ nodes, const int* __restrict__ hvc,
    const int* __restrict__ hr, const float* __restrict__ v2e,
    const char* __restrict__ ws, float* __restrict__ out, int N) {
  const unsigned short* __restrict__ H = (const unsigned short*)(ws + OFF_H);
  const unsigned short* __restrict__ M1T = (const unsigned short*)(ws + OFF_M1T);
  const unsigned short* __restrict__ WVOT = (const unsigned short*)(ws + OFF_WVOT);
  const float* __restrict__ BKQ = (const float*)(ws + OFF_BKQ);
  const float* __restrict__ BVO = (const float*)(ws + OFF_BVO);

  __shared__ __align__(16) char smem[25600 + 1088];
  char* HlB = smem;                     // 4 waves x 50 rows x 128B, swizzled
  float* sS = (float*)(smem + 25600);   // [4][68] f32 (g, then ctx, per node row)

  const int tid = threadIdx.x;
  const int wid = tid >> 6;    // 0..3  (= node within block, = d-quarter n0)
  const int lane = tid & 63;
  const int kg = lane >> 4;    // 0..3
  const int rw = lane & 15;    // 0..15
  const int nb = blockIdx.x * 4;
  const int n = min(nb + wid, N - 1);

  const int lidx = (lane < LL) ? lane : 0;
  const int idx = hvc[(size_t)n * LL + lidx] * NRAT + hr[(size_t)n * LL + lidx];

  {
    const int chunk = lane & 7;
    char* wbase = HlB + wid * 6400;
#pragma unroll
    for (int i = 0; i < 7; ++i) {
      const int s = (i < 6) ? (i * 8 + (lane >> 3)) : (42 + (lane >> 3));
      const int sidx = __shfl(idx, s, 64);
      const char* src = (const char*)H + (size_t)sidx * 128 + ((chunk ^ (s & 7)) << 4);
      __builtin_amdgcn_global_load_lds(
          (const __attribute__((address_space(1))) void*)src,
          (__attribute__((address_space(3))) void*)(wbase + ((i < 6) ? i * 1024 : 5376)),
          16, 0, 0);
    }
  }

  {
    const int node_id = nodes[min(nb + (rw & 3), N - 1)];
    const float* __restrict__ xrow = v2e + (size_t)node_id * DD;
    short8 xa[2];
#pragma unroll
    for (int ks = 0; ks < 2; ++ks) {
      xa[ks] = pack8(*(const float4*)(xrow + ks * 32 + kg * 8),
                     *(const float4*)(xrow + ks * 32 + kg * 8 + 4));
    }
    const int n0 = wid;
    f32x4 a = {0.f, 0.f, 0.f, 0.f};
#pragma unroll
    for (int ks = 0; ks < 2; ++ks) {
      const short8 bf = *(const short8*)(M1T + (n0 * 16 + rw) * DD + ks * 32 + kg * 8);
      a = __builtin_amdgcn_mfma_f32_16x16x32_bf16(xa[ks], bf, a, 0, 0, 0);
    }
    if (kg == 0) {
      const float bkqv = BKQ[n0 * 16 + rw];
#pragma unroll
      for (int r = 0; r < 4; ++r) sS[r * 68 + n0 * 16 + rw] = a[r] + bkqv;
    }
  }
  __syncthreads();
  asm volatile("s_waitcnt vmcnt(0)" ::: "memory");
  __builtin_amdgcn_sched_barrier(0);

  const unsigned short* __restrict__ wH = (const unsigned short*)(HlB + wid * 6400);

  short8 ga[2];
#pragma unroll
  for (int ks = 0; ks < 2; ++ks) {
    const float* __restrict__ gp = sS + wid * 68 + ks * 32 + kg * 8;
    ga[ks] = pack8(*(const float4*)(gp), *(const float4*)(gp + 4));
  }
  float s0, s1, s2, s3;
  {
    f32x4 a;
#pragma unroll
    for (int lt = 0; lt < 4; ++lt) {
      const int s = lt * 16 + rw;
      a = (f32x4){0.f, 0.f, 0.f, 0.f};
#pragma unroll
      for (int ks = 0; ks < 2; ++ks) {
        const int c = (ks * 4 + kg) ^ (s & 7);
        U4S8 hb;
        hb.u4 = *(const uint4*)(wH + s * 64 + c * 8);
        a = __builtin_amdgcn_mfma_f32_16x16x32_bf16(ga[ks], hb.s8, a, 0, 0, 0);
      }
      if (lt == 0) s0 = a[0];
      else if (lt == 1) s1 = a[0];
      else if (lt == 2) s2 = a[0];
      else s3 = a[0];
    }
  }
  s0 *= 0.125f; s1 *= 0.125f; s2 *= 0.125f;
  s3 = (rw < 2) ? s3 * 0.125f : -INFINITY;

  float m = fmaxf(fmaxf(s0, s1), fmaxf(s2, s3));
#pragma unroll
  for (int x = 1; x <= 8; x <<= 1) m = fmaxf(m, __shfl_xor(m, x, 64));
  float e0 = __expf(s0 - m), e1 = __expf(s1 - m), e2 = __expf(s2 - m);
  float e3 = (rw < 2) ? __expf(s3 - m) : 0.f;
  float Z = ((e0 + e1) + (e2 + e3));
#pragma unroll
  for (int x = 1; x <= 8; x <<= 1) Z += __shfl_xor(Z, x, 64);
  const float invZ = 1.f / Z;

  {
    const int sub = (lane & 7) * 2;
    const int hi3 = lane >> 3;
    float c0 = 0.f, c1 = 0.f;
#define CTX_BLOCK(EREG, BASE, CNT, CACC)                                        \
    _Pragma("unroll")                                                           \
    for (int j = 0; j < (CNT); ++j) {                                           \
      const int l = (BASE) + j;                                                 \
      const unsigned short hbb = *(const unsigned short*)(                      \
          (const char*)wH + l * 128 + (((hi3 ^ (l & 7)) << 4) | sub));          \
      CACC = fmaf(__uint_as_float(((unsigned int)hbb) << 16),                   \
                  rlanef(EREG, j), CACC);                                       \
    }
    CTX_BLOCK(e0, 0, 16, c0)
    CTX_BLOCK(e1, 16, 16, c1)
    CTX_BLOCK(e2, 32, 16, c0)
    CTX_BLOCK(e3, 48, 2, c1)
#undef CTX_BLOCK
    sS[wid * 68 + lane] = (c0 + c1) * invZ;
  }
  __syncthreads();

  {
    short8 ca[2];
#pragma unroll
    for (int ks = 0; ks < 2; ++ks) {
      const float* __restrict__ cp = sS + (rw & 3) * 68 + ks * 32 + kg * 8;
      ca[ks] = pack8(*(const float4*)(cp), *(const float4*)(cp + 4));
    }
    const int n0 = wid;
    f32x4 a = {0.f, 0.f, 0.f, 0.f};
#pragma unroll
    for (int ks = 0; ks < 2; ++ks) {
      const short8 bf = *(const short8*)(WVOT + (n0 * 16 + rw) * DD + ks * 32 + kg * 8);
      a = __builtin_amdgcn_mfma_f32_16x16x32_bf16(ca[ks], bf, a, 0, 0, 0);
    }
    if (kg == 0) {
      const float bvov = BVO[n0 * 16 + rw];
#pragma unroll
      for (int r = 0; r < 4; ++r) {
        const int node = nb + r;
        if (node < N) out[(size_t)node * DD + n0 * 16 + rw] = a[r] + bvov;
      }
    }
  }
}

extern "C" void kernel_launch(void* const* d_in, const int* in_sizes, int n_in,
                              void* d_out, int out_size, void* d_ws, size_t ws_size,
                              hipStream_t stream) {
  const int* nodes = (const int*)d_in[0];
  const int* hvc = (const int*)d_in[1];
  const int* hr = (const int*)d_in[2];
  const float* c2e = (const float*)d_in[3];
  const float* v2e = (const float*)d_in[4];
  const float* r2e = (const float*)d_in[5];
  const float* W1 = (const float*)d_in[6];
  const float* b1 = (const float*)d_in[7];
  const float* Wq = (const float*)d_in[8];
  const float* bq = (const float*)d_in[9];
  const float* Wk = (const float*)d_in[10];
  const float* bk = (const float*)d_in[11];  // unused: q·bk cancels in softmax
  const float* Wv = (const float*)d_in[12];
  const float* bv = (const float*)d_in[13];
  const float* Wo = (const float*)d_in[14];
  const float* bo = (const float*)d_in[15];
  (void)bk;
  float* out = (float*)d_out;
  char* ws = (char*)d_ws;

  const int N = in_sizes[0];

  prep_v3<<<252, 256, 0, stream>>>(c2e, r2e, W1, b1, Wq, bq, Wk, Wv, Wo, bv, bo, ws);
  vc_main<<<(N + 3) / 4, 256, 0, stream>>>(nodes, hvc, hr, v2e, ws, out, N);
}

// Round 18
// 32.328 us; speedup vs baseline: 1.8819x; 1.0860x over previous
//
#include <hip/hip_runtime.h>
#include <hip/hip_bf16.h>

#define LL 50
#define DD 64
#define NCATS 1000
#define NRAT 5

// ws byte offsets
#define OFF_H    0          // ushort[1000*5*64] = 640000 B (bf16 H table)
#define OFF_M1T  640000     // ushort[64*64] bf16 (M1t[d][e] = (Wq Wk^T)[e][d])
#define OFF_WVOT 648192     // ushort[64*64] bf16 (Wvot[d][e] = (Wv Wo)[e][d])
#define OFF_BKQ  656384     // float[64]  (Wk @ bq)
#define OFF_BVO  656640     // float[64]  (bv @ Wo + bo)

typedef __attribute__((ext_vector_type(8))) short short8;
typedef __attribute__((ext_vector_type(4))) float f32x4;

union U4S8 { uint4 u4; short8 s8; };

__device__ __forceinline__ float rlanef(float v, int l) {
  return __uint_as_float(__builtin_amdgcn_readlane(__float_as_uint(v), l));
}
// HW packed f32->bf16 (RNE)
__device__ __forceinline__ unsigned int pk2bf(float lo, float hi) {
  unsigned int r;
  asm("v_cvt_pk_bf16_f32 %0, %1, %2" : "=v"(r) : "v"(lo), "v"(hi));
  return r;
}
__device__ __forceinline__ unsigned short f2bf(float f) {
  unsigned int r;
  asm("v_cvt_pk_bf16_f32 %0, %1, %1" : "=v"(r) : "v"(f));
  return (unsigned short)r;
}
__device__ __forceinline__ short8 pack8(float4 f0, float4 f1) {
  U4S8 t;
  t.u4.x = pk2bf(f0.x, f0.y); t.u4.y = pk2bf(f0.z, f0.w);
  t.u4.z = pk2bf(f1.x, f1.y); t.u4.w = pk2bf(f1.z, f1.w);
  return t.s8;
}

// ---------------- prep_v3: BYTE-IDENTICAL to round 17 (passed) ----------------
__global__ __launch_bounds__(256) void prep_v3(
    const float* __restrict__ c2e, const float* __restrict__ r2e,
    const float* __restrict__ W1, const float* __restrict__ b1,
    const float* __restrict__ Wq, const float* __restrict__ bq,
    const float* __restrict__ Wk, const float* __restrict__ Wv,
    const float* __restrict__ Wo, const float* __restrict__ bv,
    const float* __restrict__ bo, char* __restrict__ ws) {
  unsigned short* H = (unsigned short*)(ws + OFF_H);
  unsigned short* M1T = (unsigned short*)(ws + OFF_M1T);
  unsigned short* WVOT = (unsigned short*)(ws + OFF_WVOT);
  float* BKQ = (float*)(ws + OFF_BKQ);
  float* BVO = (float*)(ws + OFF_BVO);

  const int tid = threadIdx.x;
  const int wid = tid >> 6;
  const int lane = tid & 63;
  const int kg = lane >> 4;
  const int rw = lane & 15;
  const int b = blockIdx.x;

  if (b < 250) {
    const int vc = __builtin_amdgcn_readfirstlane(b * 4 + wid);  // 250*4 = 1000
    const float* __restrict__ crow = c2e + (size_t)vc * DD;
    float ac = 0.f, q0 = 0.f, q1 = 0.f, q2 = 0.f, q3 = 0.f, q4 = 0.f;
#pragma unroll 8
    for (int e = 0; e < DD; ++e) {
      const float wa = W1[(size_t)e * DD + lane];
      const float wb = W1[(size_t)(DD + e) * DD + lane];
      ac = fmaf(crow[e], wa, ac);
      q0 = fmaf(r2e[0 * DD + e], wb, q0);
      q1 = fmaf(r2e[1 * DD + e], wb, q1);
      q2 = fmaf(r2e[2 * DD + e], wb, q2);
      q3 = fmaf(r2e[3 * DD + e], wb, q3);
      q4 = fmaf(r2e[4 * DD + e], wb, q4);
    }
    const float base = ac + b1[lane];
    unsigned short* __restrict__ hrow = H + (size_t)vc * NRAT * DD + lane;
    hrow[0 * DD] = f2bf(fmaxf(base + q0, 0.f));
    hrow[1 * DD] = f2bf(fmaxf(base + q1, 0.f));
    hrow[2 * DD] = f2bf(fmaxf(base + q2, 0.f));
    hrow[3 * DD] = f2bf(fmaxf(base + q3, 0.f));
    hrow[4 * DD] = f2bf(fmaxf(base + q4, 0.f));
  } else if (b == 250) {
    short8 aq[2];
#pragma unroll
    for (int ks = 0; ks < 2; ++ks) {
      const float* __restrict__ p = Wq + (size_t)(wid * 16 + rw) * DD + ks * 32 + kg * 8;
      aq[ks] = pack8(*(const float4*)(p), *(const float4*)(p + 4));
    }
#pragma unroll
    for (int n0 = 0; n0 < 4; ++n0) {
      f32x4 a = {0.f, 0.f, 0.f, 0.f};
#pragma unroll
      for (int ks = 0; ks < 2; ++ks) {
        const float* __restrict__ p = Wk + (size_t)(n0 * 16 + rw) * DD + ks * 32 + kg * 8;
        const short8 bf = pack8(*(const float4*)(p), *(const float4*)(p + 4));
        a = __builtin_amdgcn_mfma_f32_16x16x32_bf16(aq[ks], bf, a, 0, 0, 0);
      }
#pragma unroll
      for (int r = 0; r < 4; ++r) {
        M1T[(size_t)(n0 * 16 + rw) * DD + wid * 16 + kg * 4 + r] = f2bf(a[r]);
      }
    }
    if (wid == 0) {
      const float* __restrict__ wrow = Wk + (size_t)lane * DD;
      float a0 = 0.f, a1 = 0.f, a2 = 0.f, a3 = 0.f;
#pragma unroll
      for (int t2 = 0; t2 < DD; t2 += 4) {
        const float4 w4 = *(const float4*)(wrow + t2);
        a0 = fmaf(w4.x, bq[t2 + 0], a0);
        a1 = fmaf(w4.y, bq[t2 + 1], a1);
        a2 = fmaf(w4.z, bq[t2 + 2], a2);
        a3 = fmaf(w4.w, bq[t2 + 3], a3);
      }
      BKQ[lane] = (a0 + a1) + (a2 + a3);
    }
  } else {
    short8 ao[2];
#pragma unroll
    for (int ks = 0; ks < 2; ++ks) {
      U4S8 t4;
#pragma unroll
      for (int j = 0; j < 4; ++j) {
        const int k = ks * 32 + kg * 8 + 2 * j;
        const int col = wid * 16 + rw;
        ((unsigned int*)&t4)[j] = pk2bf(Wo[(size_t)k * DD + col],
                                        Wo[(size_t)(k + 1) * DD + col]);
      }
      ao[ks] = t4.s8;
    }
#pragma unroll
    for (int n0 = 0; n0 < 4; ++n0) {
      f32x4 a = {0.f, 0.f, 0.f, 0.f};
#pragma unroll
      for (int ks = 0; ks < 2; ++ks) {
        const float* __restrict__ p = Wv + (size_t)(n0 * 16 + rw) * DD + ks * 32 + kg * 8;
        const short8 bf = pack8(*(const float4*)(p), *(const float4*)(p + 4));
        a = __builtin_amdgcn_mfma_f32_16x16x32_bf16(ao[ks], bf, a, 0, 0, 0);
      }
#pragma unroll
      for (int r = 0; r < 4; ++r) {
        WVOT[(size_t)(wid * 16 + kg * 4 + r) * DD + n0 * 16 + rw] = f2bf(a[r]);
      }
    }
    if (wid == 0) {
      float acc = bo[lane];
#pragma unroll 8
      for (int t2 = 0; t2 < DD; ++t2) acc = fmaf(bv[t2], Wo[(size_t)t2 * DD + lane], acc);
      BVO[lane] = acc;
    }
  }
}

// ---------------- main v3: 8 nodes/block, 2 nodes/wave, counted-vmcnt pipeline ----------------
// Wave w owns nodes {nb+w, nb+4+w}. Both H-stages issued up-front; vmcnt(7)
// releases node A while B's 7 loads drain under A's compute. G/OUT MFMAs
// cover all 8 nodes at the SAME instruction count as the 4-node version.
__global__ __launch_bounds__(256, 3) void vc_main(
    const int* __restrict__ nodes, const int* __restrict__ hvc,
    const int* __restrict__ hr, const float* __restrict__ v2e,
    const char* __restrict__ ws, float* __restrict__ out, int N) {
  const unsigned short* __restrict__ H = (const unsigned short*)(ws + OFF_H);
  const unsigned short* __restrict__ M1T = (const unsigned short*)(ws + OFF_M1T);
  const unsigned short* __restrict__ WVOT = (const unsigned short*)(ws + OFF_WVOT);
  const float* __restrict__ BKQ = (const float*)(ws + OFF_BKQ);
  const float* __restrict__ BVO = (const float*)(ws + OFF_BVO);

  // 8 x 6400B H tiles + sS[8][68] f32 overlay (g then ctx; wave w owns rows w,4+w)
  __shared__ __align__(16) char smem[8 * 6400 + 8 * 68 * 4];
  char* HlB = smem;
  float* sS = (float*)(smem + 8 * 6400);

  const int tid = threadIdx.x;
  const int wid = tid >> 6;    // 0..3; d-quarter n0 == wid
  const int lane = tid & 63;
  const int kg = lane >> 4;
  const int rw = lane & 15;
  const int nb = blockIdx.x * 8;
  const int nA = min(nb + wid, N - 1);
  const int nB = min(nb + 4 + wid, N - 1);

  const int lidx = (lane < LL) ? lane : 0;
  const int idxA = hvc[(size_t)nA * LL + lidx] * NRAT + hr[(size_t)nA * LL + lidx];
  const int idxB = hvc[(size_t)nB * LL + lidx] * NRAT + hr[(size_t)nB * LL + lidx];

  // ---- stage BOTH nodes' H tiles (14 x global_load_lds) ----
  {
    const int chunk = lane & 7;
#pragma unroll
    for (int ph = 0; ph < 2; ++ph) {
      const int idx = ph ? idxB : idxA;
      char* wbase = HlB + (ph ? (4 + wid) : wid) * 6400;
#pragma unroll
      for (int i = 0; i < 7; ++i) {
        const int s = (i < 6) ? (i * 8 + (lane >> 3)) : (42 + (lane >> 3));
        const int sidx = __shfl(idx, s, 64);
        const char* src = (const char*)H + (size_t)sidx * 128 + ((chunk ^ (s & 7)) << 4);
        __builtin_amdgcn_global_load_lds(
            (const __attribute__((address_space(1))) void*)src,
            (__attribute__((address_space(3))) void*)(wbase + ((i < 6) ? i * 1024 : 5376)),
            16, 0, 0);
      }
    }
  }

  // ---- G = X @ M1 + bkq for ALL 8 nodes (same 2 MFMAs; A rows = node rw&7) ----
  {
    const int node_id = nodes[min(nb + (rw & 7), N - 1)];
    const float* __restrict__ xrow = v2e + (size_t)node_id * DD;
    short8 xa[2];
#pragma unroll
    for (int ks = 0; ks < 2; ++ks) {
      xa[ks] = pack8(*(const float4*)(xrow + ks * 32 + kg * 8),
                     *(const float4*)(xrow + ks * 32 + kg * 8 + 4));
    }
    const int n0 = wid;
    f32x4 a = {0.f, 0.f, 0.f, 0.f};
#pragma unroll
    for (int ks = 0; ks < 2; ++ks) {
      const short8 bf = *(const short8*)(M1T + (n0 * 16 + rw) * DD + ks * 32 + kg * 8);
      a = __builtin_amdgcn_mfma_f32_16x16x32_bf16(xa[ks], bf, a, 0, 0, 0);
    }
    if (kg < 2) {   // C rows 0..7 = nodes 0..7 (rows 8-15 duplicate)
      const float bkqv = BKQ[n0 * 16 + rw];
#pragma unroll
      for (int r = 0; r < 4; ++r) sS[(kg * 4 + r) * 68 + n0 * 16 + rw] = a[r] + bkqv;
    }
  }
  __syncthreads();
  asm volatile("s_waitcnt vmcnt(7)" ::: "memory");  // node A staged; B in flight
  __builtin_amdgcn_sched_barrier(0);

  // ---- two per-node phases: A (row wid), then B (row 4+wid) ----
#pragma unroll
  for (int ph = 0; ph < 2; ++ph) {
    const int myrow = ph ? (4 + wid) : wid;
    if (ph == 1) {
      asm volatile("s_waitcnt vmcnt(0)" ::: "memory");  // node B staged
      __builtin_amdgcn_sched_barrier(0);
    }
    const unsigned short* __restrict__ wH =
        (const unsigned short*)(HlB + myrow * 6400);

    short8 ga[2];
#pragma unroll
    for (int ks = 0; ks < 2; ++ks) {
      const float* __restrict__ gp = sS + myrow * 68 + ks * 32 + kg * 8;
      ga[ks] = pack8(*(const float4*)(gp), *(const float4*)(gp + 4));
    }
    float s0, s1, s2, s3;
    {
      f32x4 a;
#pragma unroll
      for (int lt = 0; lt < 4; ++lt) {
        const int s = lt * 16 + rw;
        a = (f32x4){0.f, 0.f, 0.f, 0.f};
#pragma unroll
        for (int ks = 0; ks < 2; ++ks) {
          const int c = (ks * 4 + kg) ^ (s & 7);
          U4S8 hb;
          hb.u4 = *(const uint4*)(wH + s * 64 + c * 8);
          a = __builtin_amdgcn_mfma_f32_16x16x32_bf16(ga[ks], hb.s8, a, 0, 0, 0);
        }
        if (lt == 0) s0 = a[0];
        else if (lt == 1) s1 = a[0];
        else if (lt == 2) s2 = a[0];
        else s3 = a[0];
      }
    }
    s0 *= 0.125f; s1 *= 0.125f; s2 *= 0.125f;
    s3 = (rw < 2) ? s3 * 0.125f : -INFINITY;

    float m = fmaxf(fmaxf(s0, s1), fmaxf(s2, s3));
#pragma unroll
    for (int x = 1; x <= 8; x <<= 1) m = fmaxf(m, __shfl_xor(m, x, 64));
    float e0 = __expf(s0 - m), e1 = __expf(s1 - m), e2 = __expf(s2 - m);
    float e3 = (rw < 2) ? __expf(s3 - m) : 0.f;
    float Z = ((e0 + e1) + (e2 + e3));
#pragma unroll
    for (int x = 1; x <= 8; x <<= 1) Z += __shfl_xor(Z, x, 64);
    const float invZ = 1.f / Z;

    {
      const int sub = (lane & 7) * 2;
      const int hi3 = lane >> 3;
      float c0 = 0.f, c1 = 0.f;
#define CTX_BLOCK(EREG, BASE, CNT, CACC)                                        \
      _Pragma("unroll")                                                         \
      for (int j = 0; j < (CNT); ++j) {                                         \
        const int l = (BASE) + j;                                               \
        const unsigned short hbb = *(const unsigned short*)(                    \
            (const char*)wH + l * 128 + (((hi3 ^ (l & 7)) << 4) | sub));        \
        CACC = fmaf(__uint_as_float(((unsigned int)hbb) << 16),                 \
                    rlanef(EREG, j), CACC);                                     \
      }
      CTX_BLOCK(e0, 0, 16, c0)
      CTX_BLOCK(e1, 16, 16, c1)
      CTX_BLOCK(e2, 32, 16, c0)
      CTX_BLOCK(e3, 48, 2, c1)
#undef CTX_BLOCK
      sS[myrow * 68 + lane] = (c0 + c1) * invZ;   // overwrite own row (g read done)
    }
  }
  __syncthreads();

  // ---- OUT = CTX @ Wvo + bvo for all 8 nodes (same 2 MFMAs) ----
  {
    short8 ca[2];
#pragma unroll
    for (int ks = 0; ks < 2; ++ks) {
      const float* __restrict__ cp = sS + (rw & 7) * 68 + ks * 32 + kg * 8;
      ca[ks] = pack8(*(const float4*)(cp), *(const float4*)(cp + 4));
    }
    const int n0 = wid;
    f32x4 a = {0.f, 0.f, 0.f, 0.f};
#pragma unroll
    for (int ks = 0; ks < 2; ++ks) {
      const short8 bf = *(const short8*)(WVOT + (n0 * 16 + rw) * DD + ks * 32 + kg * 8);
      a = __builtin_amdgcn_mfma_f32_16x16x32_bf16(ca[ks], bf, a, 0, 0, 0);
    }
    if (kg < 2) {   // C rows 0..7 = nodes 0..7
      const float bvov = BVO[n0 * 16 + rw];
#pragma unroll
      for (int r = 0; r < 4; ++r) {
        const int node = nb + kg * 4 + r;
        if (node < N) out[(size_t)node * DD + n0 * 16 + rw] = a[r] + bvov;
      }
    }
  }
}

extern "C" void kernel_launch(void* const* d_in, const int* in_sizes, int n_in,
                              void* d_out, int out_size, void* d_ws, size_t ws_size,
                              hipStream_t stream) {
  const int* nodes = (const int*)d_in[0];
  const int* hvc = (const int*)d_in[1];
  const int* hr = (const int*)d_in[2];
  const float* c2e = (const float*)d_in[3];
  const float* v2e = (const float*)d_in[4];
  const float* r2e = (const float*)d_in[5];
  const float* W1 = (const float*)d_in[6];
  const float* b1 = (const float*)d_in[7];
  const float* Wq = (const float*)d_in[8];
  const float* bq = (const float*)d_in[9];
  const float* Wk = (const float*)d_in[10];
  const float* bk = (const float*)d_in[11];  // unused: q·bk cancels in softmax
  const float* Wv = (const float*)d_in[12];
  const float* bv = (const float*)d_in[13];
  const float* Wo = (const float*)d_in[14];
  const float* bo = (const float*)d_in[15];
  (void)bk;
  float* out = (float*)d_out;
  char* ws = (char*)d_ws;

  const int N = in_sizes[0];

  prep_v3<<<252, 256, 0, stream>>>(c2e, r2e, W1, b1, Wq, bq, Wk, Wv, Wo, bv, bo, ws);
  vc_main<<<(N + 7) / 8, 256, 0, stream>>>(nodes, hvc, hr, v2e, ws, out, N);
}

// Round 19
// 32.211 us; speedup vs baseline: 1.8887x; 1.0036x over previous
//
#include <hip/hip_runtime.h>
#include <hip/hip_bf16.h>

#define LL 50
#define DD 64
#define NCATS 1000
#define NRAT 5

// ws byte offsets
#define OFF_H    0          // ushort[1000*5*64] = 640000 B (bf16 H table)
#define OFF_M1T  640000     // ushort[64*64] bf16 (M1t[d][e] = (Wq Wk^T)[e][d])
#define OFF_WVOT 648192     // ushort[64*64] bf16 (Wvot[d][e] = (Wv Wo)[e][d])
#define OFF_BKQ  656384     // float[64]  (Wk @ bq)
#define OFF_BVO  656640     // float[64]  (bv @ Wo + bo)

typedef __attribute__((ext_vector_type(8))) short short8;
typedef __attribute__((ext_vector_type(4))) float f32x4;

union U4S8 { uint4 u4; short8 s8; };

__device__ __forceinline__ float rlanef(float v, int l) {
  return __uint_as_float(__builtin_amdgcn_readlane(__float_as_uint(v), l));
}
// HW packed f32->bf16 (RNE)
__device__ __forceinline__ unsigned int pk2bf(float lo, float hi) {
  unsigned int r;
  asm("v_cvt_pk_bf16_f32 %0, %1, %2" : "=v"(r) : "v"(lo), "v"(hi));
  return r;
}
__device__ __forceinline__ unsigned short f2bf(float f) {
  unsigned int r;
  asm("v_cvt_pk_bf16_f32 %0, %1, %1" : "=v"(r) : "v"(f));
  return (unsigned short)r;
}
__device__ __forceinline__ short8 pack8(float4 f0, float4 f1) {
  U4S8 t;
  t.u4.x = pk2bf(f0.x, f0.y); t.u4.y = pk2bf(f0.z, f0.w);
  t.u4.z = pk2bf(f1.x, f1.y); t.u4.w = pk2bf(f1.z, f1.w);
  return t.s8;
}

// ---------------- prep_v3: BYTE-IDENTICAL to round 17/18 (passed) ----------------
__global__ __launch_bounds__(256) void prep_v3(
    const float* __restrict__ c2e, const float* __restrict__ r2e,
    const float* __restrict__ W1, const float* __restrict__ b1,
    const float* __restrict__ Wq, const float* __restrict__ bq,
    const float* __restrict__ Wk, const float* __restrict__ Wv,
    const float* __restrict__ Wo, const float* __restrict__ bv,
    const float* __restrict__ bo, char* __restrict__ ws) {
  unsigned short* H = (unsigned short*)(ws + OFF_H);
  unsigned short* M1T = (unsigned short*)(ws + OFF_M1T);
  unsigned short* WVOT = (unsigned short*)(ws + OFF_WVOT);
  float* BKQ = (float*)(ws + OFF_BKQ);
  float* BVO = (float*)(ws + OFF_BVO);

  const int tid = threadIdx.x;
  const int wid = tid >> 6;
  const int lane = tid & 63;
  const int kg = lane >> 4;
  const int rw = lane & 15;
  const int b = blockIdx.x;

  if (b < 250) {
    const int vc = __builtin_amdgcn_readfirstlane(b * 4 + wid);  // 250*4 = 1000
    const float* __restrict__ crow = c2e + (size_t)vc * DD;
    float ac = 0.f, q0 = 0.f, q1 = 0.f, q2 = 0.f, q3 = 0.f, q4 = 0.f;
#pragma unroll 8
    for (int e = 0; e < DD; ++e) {
      const float wa = W1[(size_t)e * DD + lane];
      const float wb = W1[(size_t)(DD + e) * DD + lane];
      ac = fmaf(crow[e], wa, ac);
      q0 = fmaf(r2e[0 * DD + e], wb, q0);
      q1 = fmaf(r2e[1 * DD + e], wb, q1);
      q2 = fmaf(r2e[2 * DD + e], wb, q2);
      q3 = fmaf(r2e[3 * DD + e], wb, q3);
      q4 = fmaf(r2e[4 * DD + e], wb, q4);
    }
    const float base = ac + b1[lane];
    unsigned short* __restrict__ hrow = H + (size_t)vc * NRAT * DD + lane;
    hrow[0 * DD] = f2bf(fmaxf(base + q0, 0.f));
    hrow[1 * DD] = f2bf(fmaxf(base + q1, 0.f));
    hrow[2 * DD] = f2bf(fmaxf(base + q2, 0.f));
    hrow[3 * DD] = f2bf(fmaxf(base + q3, 0.f));
    hrow[4 * DD] = f2bf(fmaxf(base + q4, 0.f));
  } else if (b == 250) {
    short8 aq[2];
#pragma unroll
    for (int ks = 0; ks < 2; ++ks) {
      const float* __restrict__ p = Wq + (size_t)(wid * 16 + rw) * DD + ks * 32 + kg * 8;
      aq[ks] = pack8(*(const float4*)(p), *(const float4*)(p + 4));
    }
#pragma unroll
    for (int n0 = 0; n0 < 4; ++n0) {
      f32x4 a = {0.f, 0.f, 0.f, 0.f};
#pragma unroll
      for (int ks = 0; ks < 2; ++ks) {
        const float* __restrict__ p = Wk + (size_t)(n0 * 16 + rw) * DD + ks * 32 + kg * 8;
        const short8 bf = pack8(*(const float4*)(p), *(const float4*)(p + 4));
        a = __builtin_amdgcn_mfma_f32_16x16x32_bf16(aq[ks], bf, a, 0, 0, 0);
      }
#pragma unroll
      for (int r = 0; r < 4; ++r) {
        M1T[(size_t)(n0 * 16 + rw) * DD + wid * 16 + kg * 4 + r] = f2bf(a[r]);
      }
    }
    if (wid == 0) {
      const float* __restrict__ wrow = Wk + (size_t)lane * DD;
      float a0 = 0.f, a1 = 0.f, a2 = 0.f, a3 = 0.f;
#pragma unroll
      for (int t2 = 0; t2 < DD; t2 += 4) {
        const float4 w4 = *(const float4*)(wrow + t2);
        a0 = fmaf(w4.x, bq[t2 + 0], a0);
        a1 = fmaf(w4.y, bq[t2 + 1], a1);
        a2 = fmaf(w4.z, bq[t2 + 2], a2);
        a3 = fmaf(w4.w, bq[t2 + 3], a3);
      }
      BKQ[lane] = (a0 + a1) + (a2 + a3);
    }
  } else {
    short8 ao[2];
#pragma unroll
    for (int ks = 0; ks < 2; ++ks) {
      U4S8 t4;
#pragma unroll
      for (int j = 0; j < 4; ++j) {
        const int k = ks * 32 + kg * 8 + 2 * j;
        const int col = wid * 16 + rw;
        ((unsigned int*)&t4)[j] = pk2bf(Wo[(size_t)k * DD + col],
                                        Wo[(size_t)(k + 1) * DD + col]);
      }
      ao[ks] = t4.s8;
    }
#pragma unroll
    for (int n0 = 0; n0 < 4; ++n0) {
      f32x4 a = {0.f, 0.f, 0.f, 0.f};
#pragma unroll
      for (int ks = 0; ks < 2; ++ks) {
        const float* __restrict__ p = Wv + (size_t)(n0 * 16 + rw) * DD + ks * 32 + kg * 8;
        const short8 bf = pack8(*(const float4*)(p), *(const float4*)(p + 4));
        a = __builtin_amdgcn_mfma_f32_16x16x32_bf16(ao[ks], bf, a, 0, 0, 0);
      }
#pragma unroll
      for (int r = 0; r < 4; ++r) {
        WVOT[(size_t)(wid * 16 + kg * 4 + r) * DD + n0 * 16 + rw] = f2bf(a[r]);
      }
    }
    if (wid == 0) {
      float acc = bo[lane];
#pragma unroll 8
      for (int t2 = 0; t2 < DD; ++t2) acc = fmaf(bv[t2], Wo[(size_t)t2 * DD + lane], acc);
      BVO[lane] = acc;
    }
  }
}

// ---------------- main v3.1: r18 structure + precomputed ctx base addresses ----------------
// ONLY change vs r18: ctx loop addressing. addr(l) = q*1024 + base[j] with
// l = q*8+j; base[0..7] precomputed once -> ds_read_u16 with compile-time
// immediate offset q*1024, zero per-iter address VALU. Same accumulation order
// (bit-identical result).
__global__ __launch_bounds__(256, 3) void vc_main(
    const int* __restrict__ nodes, const int* __restrict__ hvc,
    const int* __restrict__ hr, const float* __restrict__ v2e,
    const char* __restrict__ ws, float* __restrict__ out, int N) {
  const unsigned short* __restrict__ H = (const unsigned short*)(ws + OFF_H);
  const unsigned short* __restrict__ M1T = (const unsigned short*)(ws + OFF_M1T);
  const unsigned short* __restrict__ WVOT = (const unsigned short*)(ws + OFF_WVOT);
  const float* __restrict__ BKQ = (const float*)(ws + OFF_BKQ);
  const float* __restrict__ BVO = (const float*)(ws + OFF_BVO);

  __shared__ __align__(16) char smem[8 * 6400 + 8 * 68 * 4];
  char* HlB = smem;
  float* sS = (float*)(smem + 8 * 6400);

  const int tid = threadIdx.x;
  const int wid = tid >> 6;    // 0..3; d-quarter n0 == wid
  const int lane = tid & 63;
  const int kg = lane >> 4;
  const int rw = lane & 15;
  const int nb = blockIdx.x * 8;
  const int nA = min(nb + wid, N - 1);
  const int nB = min(nb + 4 + wid, N - 1);

  const int lidx = (lane < LL) ? lane : 0;
  const int idxA = hvc[(size_t)nA * LL + lidx] * NRAT + hr[(size_t)nA * LL + lidx];
  const int idxB = hvc[(size_t)nB * LL + lidx] * NRAT + hr[(size_t)nB * LL + lidx];

  // ---- stage BOTH nodes' H tiles (14 x global_load_lds) ----
  {
    const int chunk = lane & 7;
#pragma unroll
    for (int ph = 0; ph < 2; ++ph) {
      const int idx = ph ? idxB : idxA;
      char* wbase = HlB + (ph ? (4 + wid) : wid) * 6400;
#pragma unroll
      for (int i = 0; i < 7; ++i) {
        const int s = (i < 6) ? (i * 8 + (lane >> 3)) : (42 + (lane >> 3));
        const int sidx = __shfl(idx, s, 64);
        const char* src = (const char*)H + (size_t)sidx * 128 + ((chunk ^ (s & 7)) << 4);
        __builtin_amdgcn_global_load_lds(
            (const __attribute__((address_space(1))) void*)src,
            (__attribute__((address_space(3))) void*)(wbase + ((i < 6) ? i * 1024 : 5376)),
            16, 0, 0);
      }
    }
  }

  // ---- G = X @ M1 + bkq for ALL 8 nodes ----
  {
    const int node_id = nodes[min(nb + (rw & 7), N - 1)];
    const float* __restrict__ xrow = v2e + (size_t)node_id * DD;
    short8 xa[2];
#pragma unroll
    for (int ks = 0; ks < 2; ++ks) {
      xa[ks] = pack8(*(const float4*)(xrow + ks * 32 + kg * 8),
                     *(const float4*)(xrow + ks * 32 + kg * 8 + 4));
    }
    const int n0 = wid;
    f32x4 a = {0.f, 0.f, 0.f, 0.f};
#pragma unroll
    for (int ks = 0; ks < 2; ++ks) {
      const short8 bf = *(const short8*)(M1T + (n0 * 16 + rw) * DD + ks * 32 + kg * 8);
      a = __builtin_amdgcn_mfma_f32_16x16x32_bf16(xa[ks], bf, a, 0, 0, 0);
    }
    if (kg < 2) {   // C rows 0..7 = nodes 0..7
      const float bkqv = BKQ[n0 * 16 + rw];
#pragma unroll
      for (int r = 0; r < 4; ++r) sS[(kg * 4 + r) * 68 + n0 * 16 + rw] = a[r] + bkqv;
    }
  }
  __syncthreads();
  asm volatile("s_waitcnt vmcnt(7)" ::: "memory");  // node A staged; B in flight
  __builtin_amdgcn_sched_barrier(0);

  // ---- ctx base offsets: addr(l) = (l>>3)*1024 + baseo[l&7] (precomputed) ----
  const int sub = (lane & 7) * 2;
  const int hi3 = lane >> 3;
  int baseo[8];
#pragma unroll
  for (int j = 0; j < 8; ++j) baseo[j] = j * 128 + (((hi3 ^ j) << 4) | sub);

  // ---- two per-node phases: A (row wid), then B (row 4+wid) ----
#pragma unroll
  for (int ph = 0; ph < 2; ++ph) {
    const int myrow = ph ? (4 + wid) : wid;
    if (ph == 1) {
      asm volatile("s_waitcnt vmcnt(0)" ::: "memory");  // node B staged
      __builtin_amdgcn_sched_barrier(0);
    }
    const unsigned short* __restrict__ wH =
        (const unsigned short*)(HlB + myrow * 6400);

    short8 ga[2];
#pragma unroll
    for (int ks = 0; ks < 2; ++ks) {
      const float* __restrict__ gp = sS + myrow * 68 + ks * 32 + kg * 8;
      ga[ks] = pack8(*(const float4*)(gp), *(const float4*)(gp + 4));
    }
    float s0, s1, s2, s3;
    {
      f32x4 a;
#pragma unroll
      for (int lt = 0; lt < 4; ++lt) {
        const int s = lt * 16 + rw;
        a = (f32x4){0.f, 0.f, 0.f, 0.f};
#pragma unroll
        for (int ks = 0; ks < 2; ++ks) {
          const int c = (ks * 4 + kg) ^ (s & 7);
          U4S8 hb;
          hb.u4 = *(const uint4*)(wH + s * 64 + c * 8);
          a = __builtin_amdgcn_mfma_f32_16x16x32_bf16(ga[ks], hb.s8, a, 0, 0, 0);
        }
        if (lt == 0) s0 = a[0];
        else if (lt == 1) s1 = a[0];
        else if (lt == 2) s2 = a[0];
        else s3 = a[0];
      }
    }
    s0 *= 0.125f; s1 *= 0.125f; s2 *= 0.125f;
    s3 = (rw < 2) ? s3 * 0.125f : -INFINITY;

    float m = fmaxf(fmaxf(s0, s1), fmaxf(s2, s3));
#pragma unroll
    for (int x = 1; x <= 8; x <<= 1) m = fmaxf(m, __shfl_xor(m, x, 64));
    float e0 = __expf(s0 - m), e1 = __expf(s1 - m), e2 = __expf(s2 - m);
    float e3 = (rw < 2) ? __expf(s3 - m) : 0.f;
    float Z = ((e0 + e1) + (e2 + e3));
#pragma unroll
    for (int x = 1; x <= 8; x <<= 1) Z += __shfl_xor(Z, x, 64);
    const float invZ = 1.f / Z;

    {
      const char* __restrict__ wHb = (const char*)wH;
      float c0 = 0.f, c1 = 0.f;
#define CTX_BLOCK(EREG, BASE, CNT, CACC)                                        \
      _Pragma("unroll")                                                         \
      for (int j = 0; j < (CNT); ++j) {                                         \
        const int l = (BASE) + j;                                               \
        const unsigned short hbb = *(const unsigned short*)(                    \
            wHb + baseo[l & 7] + (l >> 3) * 1024);                              \
        CACC = fmaf(__uint_as_float(((unsigned int)hbb) << 16),                 \
                    rlanef(EREG, j), CACC);                                     \
      }
      CTX_BLOCK(e0, 0, 16, c0)
      CTX_BLOCK(e1, 16, 16, c1)
      CTX_BLOCK(e2, 32, 16, c0)
      CTX_BLOCK(e3, 48, 2, c1)
#undef CTX_BLOCK
      sS[myrow * 68 + lane] = (c0 + c1) * invZ;   // overwrite own row
    }
  }
  __syncthreads();

  // ---- OUT = CTX @ Wvo + bvo for all 8 nodes ----
  {
    short8 ca[2];
#pragma unroll
    for (int ks = 0; ks < 2; ++ks) {
      const float* __restrict__ cp = sS + (rw & 7) * 68 + ks * 32 + kg * 8;
      ca[ks] = pack8(*(const float4*)(cp), *(const float4*)(cp + 4));
    }
    const int n0 = wid;
    f32x4 a = {0.f, 0.f, 0.f, 0.f};
#pragma unroll
    for (int ks = 0; ks < 2; ++ks) {
      const short8 bf = *(const short8*)(WVOT + (n0 * 16 + rw) * DD + ks * 32 + kg * 8);
      a = __builtin_amdgcn_mfma_f32_16x16x32_bf16(ca[ks], bf, a, 0, 0, 0);
    }
    if (kg < 2) {   // C rows 0..7 = nodes 0..7
      const float bvov = BVO[n0 * 16 + rw];
#pragma unroll
      for (int r = 0; r < 4; ++r) {
        const int node = nb + kg * 4 + r;
        if (node < N) out[(size_t)node * DD + n0 * 16 + rw] = a[r] + bvov;
      }
    }
  }
}

extern "C" void kernel_launch(void* const* d_in, const int* in_sizes, int n_in,
                              void* d_out, int out_size, void* d_ws, size_t ws_size,
                              hipStream_t stream) {
  const int* nodes = (const int*)d_in[0];
  const int* hvc = (const int*)d_in[1];
  const int* hr = (const int*)d_in[2];
  const float* c2e = (const float*)d_in[3];
  const float* v2e = (const float*)d_in[4];
  const float* r2e = (const float*)d_in[5];
  const float* W1 = (const float*)d_in[6];
  const float* b1 = (const float*)d_in[7];
  const float* Wq = (const float*)d_in[8];
  const float* bq = (const float*)d_in[9];
  const float* Wk = (const float*)d_in[10];
  const float* bk = (const float*)d_in[11];  // unused: q·bk cancels in softmax
  const float* Wv = (const float*)d_in[12];
  const float* bv = (const float*)d_in[13];
  const float* Wo = (const float*)d_in[14];
  const float* bo = (const float*)d_in[15];
  (void)bk;
  float* out = (float*)d_out;
  char* ws = (char*)d_ws;

  const int N = in_sizes[0];

  prep_v3<<<252, 256, 0, stream>>>(c2e, r2e, W1, b1, Wq, bq, Wk, Wv, Wo, bv, bo, ws);
  vc_main<<<(N + 7) / 8, 256, 0, stream>>>(nodes, hvc, hr, v2e, ws, out, N);
}